// Round 11
// baseline (507.771 us; speedup 1.0000x reference)
//
#include <hip/hip_runtime.h>

#define NN 20000      // nodes
#define NE 640000     // edges (without self loops)
#define NEE 660000    // edges + self loops
#define NP 200000     // drug pairs
#define NEG 0.2f      // leaky relu slope

// ---------------- CSR build ----------------
__global__ void k_hist(const int* __restrict__ ei, int* __restrict__ cnt) {
  int i = blockIdx.x * 256 + threadIdx.x;
  if (i >= NEE) return;
  int d = (i < NE) ? ei[NE + i] : (i - NE);
  atomicAdd(&cnt[d], 1);
}

__global__ __launch_bounds__(1024) void k_scan(const int* __restrict__ cnt, int* __restrict__ rp) {
  __shared__ int ps[1024];
  const int CH = 20;  // 1024*20 = 20480 >= 20000
  int t = threadIdx.x;
  int lo = t * CH, hi = lo + CH;
  if (hi > NN) hi = NN;
  if (lo > NN) lo = NN;
  int s = 0;
  for (int i = lo; i < hi; ++i) s += cnt[i];
  ps[t] = s;
  __syncthreads();
  for (int off = 1; off < 1024; off <<= 1) {
    int v = (t >= off) ? ps[t - off] : 0;
    __syncthreads();
    ps[t] += v;
    __syncthreads();
  }
  int run = (t > 0) ? ps[t - 1] : 0;
  for (int i = lo; i < hi; ++i) { rp[i] = run; run += cnt[i]; }
  if (t == 1023) rp[NN] = ps[1023];
}

__global__ void k_scatter(const int* __restrict__ ei, const int* __restrict__ rp,
                          int* __restrict__ cur, int* __restrict__ col) {
  int i = blockIdx.x * 256 + threadIdx.x;
  if (i >= NEE) return;
  int s, d;
  if (i < NE) { s = ei[i]; d = ei[NE + i]; } else { s = i - NE; d = s; }
  int pos = atomicAdd(&cur[d], 1);
  col[rp[d] + pos] = s;
}

// ---------------- GEMM1: h1 = x @ W1  [20000,256]x[256,256], + alphas ----------------
// h1 is stored HEAD-MAJOR: h1h[head][n][64] so each head's slice is a contiguous 5 MB.
__global__ __launch_bounds__(256) void k_gemm1(
    const float* __restrict__ x, const float* __restrict__ W1,
    const float* __restrict__ as1, const float* __restrict__ ad1,
    float* __restrict__ h1h, float* __restrict__ AS1, float* __restrict__ AD1) {
  __shared__ float xsT[256][20];  // [k][row], pad 20 keeps 16B row alignment
  int c = threadIdx.x;            // output col 0..255
  int base = blockIdx.x * 16;     // 16 rows per block
  for (int i = threadIdx.x; i < 16 * 256; i += 256) {
    int r = i >> 8, k = i & 255;
    xsT[k][r] = x[(base + r) * 256 + k];
  }
  __syncthreads();
  float acc[16];
#pragma unroll
  for (int r = 0; r < 16; ++r) acc[r] = 0.f;
#pragma unroll 2
  for (int k = 0; k < 256; ++k) {
    float wv = W1[k * 256 + c];
    const float4* xr = (const float4*)&xsT[k][0];
    float4 x0 = xr[0], x1 = xr[1], x2 = xr[2], x3 = xr[3];
    acc[0] += x0.x * wv; acc[1] += x0.y * wv; acc[2] += x0.z * wv; acc[3] += x0.w * wv;
    acc[4] += x1.x * wv; acc[5] += x1.y * wv; acc[6] += x1.z * wv; acc[7] += x1.w * wv;
    acc[8] += x2.x * wv; acc[9] += x2.y * wv; acc[10] += x2.z * wv; acc[11] += x2.w * wv;
    acc[12] += x3.x * wv; acc[13] += x3.y * wv; acc[14] += x3.z * wv; acc[15] += x3.w * wv;
  }
  int head = c >> 6, cc = c & 63;
  float asv = as1[c];  // flat [head][c&63] == c
  float adv = ad1[c];
#pragma unroll
  for (int r = 0; r < 16; ++r) {
    h1h[((size_t)head * NN + (base + r)) * 64 + cc] = acc[r];
    float vs = acc[r] * asv, vd = acc[r] * adv;
#pragma unroll
    for (int off = 32; off > 0; off >>= 1) {
      vs += __shfl_xor(vs, off);
      vd += __shfl_xor(vd, off);
    }
    if ((c & 63) == 0) {
      AS1[(base + r) * 4 + head] = vs;
      AD1[(base + r) * 4 + head] = vd;
    }
  }
}

// ---------------- GAT layer-1 aggregation, FUSED edge weights: 4 edges x 16 lanes --------
__global__ __launch_bounds__(256) void k_agg1(
    const int* __restrict__ rp, const int* __restrict__ col,
    const float* __restrict__ AS1, const float* __restrict__ AD1,
    const float* __restrict__ h1h, const float* __restrict__ b1,
    float* __restrict__ out) {
  int wave = threadIdx.x >> 6, lane = threadIdx.x & 63;
  int head = blockIdx.y;
  int n = blockIdx.x * 4 + wave;
  int g = lane >> 4, c4 = (lane & 15) * 4;
  int e0 = rp[n], e1 = rp[n + 1];
  const float* hs = h1h + (size_t)head * NN * 64;
  float adv = AD1[n * 4 + head];
  float ax = 0.f, ay = 0.f, az = 0.f, aw = 0.f, den = 0.f;
#pragma unroll 2
  for (int e = e0; e < e1; e += 4) {
    int ee = e + g;
    bool valid = ee < e1;
    int ec = valid ? ee : e1 - 1;
    int s = col[ec];
    float ev = AS1[s * 4 + head] + adv;
    ev = ev > 0.f ? ev : NEG * ev;
    float p = valid ? __expf(ev) : 0.f;
    float4 hv = *(const float4*)(hs + (size_t)s * 64 + c4);
    ax += p * hv.x; ay += p * hv.y; az += p * hv.z; aw += p * hv.w;
    den += p;
  }
  ax += __shfl_xor(ax, 16); ax += __shfl_xor(ax, 32);
  ay += __shfl_xor(ay, 16); ay += __shfl_xor(ay, 32);
  az += __shfl_xor(az, 16); az += __shfl_xor(az, 32);
  aw += __shfl_xor(aw, 16); aw += __shfl_xor(aw, 32);
  den += __shfl_xor(den, 16); den += __shfl_xor(den, 32);
  if (lane < 16) {
    float inv = 1.f / den;
    int cbase = head * 64 + c4;
    float4 bv = *(const float4*)(b1 + cbase);
    float4 o;
    o.x = ax * inv + bv.x; o.y = ay * inv + bv.y;
    o.z = az * inv + bv.z; o.w = aw * inv + bv.w;
    o.x = o.x > 0.f ? o.x : __expf(o.x) - 1.f;
    o.y = o.y > 0.f ? o.y : __expf(o.y) - 1.f;
    o.z = o.z > 0.f ? o.z : __expf(o.z) - 1.f;
    o.w = o.w > 0.f ? o.w : __expf(o.w) - 1.f;
    *(float4*)(out + (size_t)n * 256 + cbase) = o;
  }
}

// ---------------- GEMM2: h2 = h1act @ W2  [20000,256]x[256,64], + alphas ----------------
__global__ __launch_bounds__(256) void k_gemm2(
    const float* __restrict__ h1a, const float* __restrict__ W2,
    const float* __restrict__ as2, const float* __restrict__ ad2,
    float* __restrict__ h2, float* __restrict__ AS2, float* __restrict__ AD2) {
  __shared__ float xsT[256][20];
  int tid = threadIdx.x;
  int c = tid & 63, w = tid >> 6;  // wave w handles rows 4w..4w+3
  int base = blockIdx.x * 16;
  for (int i = tid; i < 16 * 256; i += 256) {
    int r = i >> 8, k = i & 255;
    xsT[k][r] = h1a[(base + r) * 256 + k];
  }
  __syncthreads();
  float acc[4] = {0.f, 0.f, 0.f, 0.f};
#pragma unroll 2
  for (int k = 0; k < 256; ++k) {
    float wv = W2[k * 64 + c];
    float4 xv = *(const float4*)&xsT[k][w * 4];
    acc[0] += xv.x * wv; acc[1] += xv.y * wv; acc[2] += xv.z * wv; acc[3] += xv.w * wv;
  }
  float asv = as2[c], adv = ad2[c];
#pragma unroll
  for (int rr = 0; rr < 4; ++rr) {
    int row = base + w * 4 + rr;
    h2[row * 64 + c] = acc[rr];
    float vs = acc[rr] * asv, vd = acc[rr] * adv;
#pragma unroll
    for (int off = 32; off > 0; off >>= 1) {
      vs += __shfl_xor(vs, off);
      vd += __shfl_xor(vd, off);
    }
    if (c == 0) { AS2[row] = vs; AD2[row] = vd; }
  }
}

// ---------------- GAT layer-2 aggregation, FUSED edge weights ----------------
__global__ __launch_bounds__(256) void k_agg2(
    const int* __restrict__ rp, const int* __restrict__ col,
    const float* __restrict__ AS2, const float* __restrict__ AD2,
    const float* __restrict__ h2, const float* __restrict__ b2,
    float* __restrict__ out) {
  int wave = threadIdx.x >> 6, lane = threadIdx.x & 63;
  int n = blockIdx.x * 4 + wave;
  int g = lane >> 4, c4 = (lane & 15) * 4;
  int e0 = rp[n], e1 = rp[n + 1];
  float adv = AD2[n];
  float ax = 0.f, ay = 0.f, az = 0.f, aw = 0.f, den = 0.f;
#pragma unroll 2
  for (int e = e0; e < e1; e += 4) {
    int ee = e + g;
    bool valid = ee < e1;
    int ec = valid ? ee : e1 - 1;
    int s = col[ec];
    float ev = AS2[s] + adv;
    ev = ev > 0.f ? ev : NEG * ev;
    float p = valid ? __expf(ev) : 0.f;
    float4 hv = *(const float4*)(h2 + (size_t)s * 64 + c4);
    ax += p * hv.x; ay += p * hv.y; az += p * hv.z; aw += p * hv.w;
    den += p;
  }
  ax += __shfl_xor(ax, 16); ax += __shfl_xor(ax, 32);
  ay += __shfl_xor(ay, 16); ay += __shfl_xor(ay, 32);
  az += __shfl_xor(az, 16); az += __shfl_xor(az, 32);
  aw += __shfl_xor(aw, 16); aw += __shfl_xor(aw, 32);
  den += __shfl_xor(den, 16); den += __shfl_xor(den, 32);
  if (lane < 16) {
    float inv = 1.f / den;
    float4 bv = *(const float4*)(b2 + c4);
    float4 o;
    o.x = ax * inv + bv.x; o.y = ay * inv + bv.y;
    o.z = az * inv + bv.z; o.w = aw * inv + bv.w;
    o.x = o.x > 0.f ? o.x : __expf(o.x) - 1.f;
    o.y = o.y > 0.f ? o.y : __expf(o.y) - 1.f;
    o.z = o.z > 0.f ? o.z : __expf(o.z) - 1.f;
    o.w = o.w > 0.f ? o.w : __expf(o.w) - 1.f;
    *(float4*)(out + (size_t)n * 64 + c4) = o;
  }
}

// ---------------- pair MLP v11: v6 wave-split + LDS comb staging ----------------
// Block = 128 threads = 2 waves, 64 pairs (NP = 64*3125 exactly). Thread (pp, hu):
// pair pp = tid&63, half hu = wave id. comb staged COOPERATIVELY into LDS cT[pair][k]
// (row-contiguous, stride 132 -> quarter-wave b128 reads are ~2-way aliased = free):
// each thread stages half hu of its pair once -> no duplicate gathers, and the layer-1
// inner loop has ZERO global loads: 1 ds_read_b128 per 128 FMA. Live set acc[32]+cv
// ~ 45 VGPR -> immune to the allocator's small-budget choices (v4/v7/v10 lesson).
// z written back into cT cols 0-63 after a barrier (LDS reuse). Weights remain
// thread-uniform (hu readfirstlane'd) with compile-time-consecutive inner index ->
// batched s_load_dwordxN on the scalar pipe, dual-issued with v_fmac (v6-proven).
// LDS 33.8 KB -> 4 blocks/CU.
#define PB 128

__global__ __launch_bounds__(PB, 4) void k_pairs(
    const int* __restrict__ pairs, const float* __restrict__ h2a,
    const float* __restrict__ Wp1, const float* __restrict__ bp1,
    const float* __restrict__ Wp2, const float* __restrict__ bp2,
    float* __restrict__ out) {
  __shared__ float cT[64][132];  // [pair][k]; reused as z[pair][t] (cols 0-63) after L1
  int tid = threadIdx.x;
  int pp = tid & 63;                                      // pair within block
  int hu = __builtin_amdgcn_readfirstlane(tid >> 6);      // wave id 0/1, provably uniform
  int p = blockIdx.x * 64 + pp;

  // ---- stage comb: thread (pp,hu) loads half hu (64 floats) of pair pp's comb
  {
    int node = pairs[2 * p + hu];                          // hu=0 -> src node, hu=1 -> dst
    const float4* src = (const float4*)(h2a + (size_t)node * 64);
    float4* drow = (float4*)&cT[pp][hu * 64];              // 528B row stride: 16B aligned
#pragma unroll
    for (int m = 0; m < 16; ++m) drow[m] = src[m];
  }
  __syncthreads();

  // ---- layer 1: z[hu*32+u] = relu(bp1 + sum_k comb[k]*Wp1[k][hu*32+u])
  {
    float acc[32];
#pragma unroll
    for (int u = 0; u < 32; ++u) acc[u] = bp1[hu * 32 + u];
#pragma unroll 4
    for (int k4 = 0; k4 < 128; k4 += 4) {
      float4 cv = *(const float4*)&cT[pp][k4];
      const float* wb = Wp1 + (size_t)k4 * 64 + hu * 32;   // uniform, u-consecutive
#pragma unroll
      for (int u = 0; u < 32; ++u) acc[u] += cv.x * wb[u];
#pragma unroll
      for (int u = 0; u < 32; ++u) acc[u] += cv.y * wb[64 + u];
#pragma unroll
      for (int u = 0; u < 32; ++u) acc[u] += cv.z * wb[128 + u];
#pragma unroll
      for (int u = 0; u < 32; ++u) acc[u] += cv.w * wb[192 + u];
    }
    __syncthreads();  // all cT reads complete before z overwrites cols 0-63
#pragma unroll
    for (int u = 0; u < 32; ++u) cT[pp][hu * 32 + u] = fmaxf(acc[u], 0.f);
  }
  __syncthreads();

  // ---- layer 2: out[p][hu*43+j] = bp2 + sum_t z[t]*Wp2[t][hu*43+j]
  {
    float acc2[43];
#pragma unroll
    for (int j = 0; j < 43; ++j) acc2[j] = bp2[hu * 43 + j];
#pragma unroll 2
    for (int t4 = 0; t4 < 64; t4 += 4) {
      float4 zv = *(const float4*)&cT[pp][t4];
      const float* wb = Wp2 + (size_t)t4 * 86 + hu * 43;   // uniform, j-consecutive
#pragma unroll
      for (int j = 0; j < 43; ++j) acc2[j] += zv.x * wb[j];
#pragma unroll
      for (int j = 0; j < 43; ++j) acc2[j] += zv.y * wb[86 + j];
#pragma unroll
      for (int j = 0; j < 43; ++j) acc2[j] += zv.z * wb[172 + j];
#pragma unroll
      for (int j = 0; j < 43; ++j) acc2[j] += zv.w * wb[258 + j];
    }
#pragma unroll
    for (int j = 0; j < 43; ++j) out[(size_t)p * 86 + hu * 43 + j] = acc2[j];
  }
}

extern "C" void kernel_launch(void* const* d_in, const int* in_sizes, int n_in,
                              void* d_out, int out_size, void* d_ws, size_t ws_size,
                              hipStream_t stream) {
  (void)in_sizes; (void)n_in; (void)out_size; (void)ws_size;
  const float* x      = (const float*)d_in[0];
  const int*   ei     = (const int*)d_in[1];
  const int*   pairs  = (const int*)d_in[2];
  const float* W1     = (const float*)d_in[3];
  const float* a_src1 = (const float*)d_in[4];
  const float* a_dst1 = (const float*)d_in[5];
  const float* b1     = (const float*)d_in[6];
  const float* W2     = (const float*)d_in[7];
  const float* a_src2 = (const float*)d_in[8];
  const float* a_dst2 = (const float*)d_in[9];
  const float* b2     = (const float*)d_in[10];
  const float* Wp1    = (const float*)d_in[11];
  const float* bp1    = (const float*)d_in[12];
  const float* Wp2    = (const float*)d_in[13];
  const float* bp2    = (const float*)d_in[14];
  float* out = (float*)d_out;

  char* w = (char*)d_ws;
  auto alloc = [&](size_t bytes) -> void* {
    void* pp = (void*)w;
    w += (bytes + 255) & ~(size_t)255;
    return pp;
  };
  float* h1    = (float*)alloc((size_t)NN * 256 * 4);  // head-major [4][NN][64]
  float* AS1   = (float*)alloc((size_t)NN * 4 * 4);
  float* AD1   = (float*)alloc((size_t)NN * 4 * 4);
  float* h1agg = (float*)alloc((size_t)NN * 256 * 4);
  float* h2    = (float*)alloc((size_t)NN * 64 * 4);
  float* AS2   = (float*)alloc((size_t)NN * 4);
  float* AD2   = (float*)alloc((size_t)NN * 4);
  float* h2agg = (float*)alloc((size_t)NN * 64 * 4);
  int*   rp    = (int*)alloc((size_t)(NN + 1) * 4);
  int*   cnt   = (int*)alloc((size_t)NN * 4);
  int*   cur   = (int*)alloc((size_t)NN * 4);
  int*   col   = (int*)alloc((size_t)NEE * 4);

  hipMemsetAsync(cnt, 0, (size_t)NN * 4, stream);
  hipMemsetAsync(cur, 0, (size_t)NN * 4, stream);

  const int EB = (NEE + 255) / 256;  // 2579
  k_hist<<<EB, 256, 0, stream>>>(ei, cnt);
  k_scan<<<1, 1024, 0, stream>>>(cnt, rp);
  k_scatter<<<EB, 256, 0, stream>>>(ei, rp, cur, col);

  k_gemm1<<<NN / 16, 256, 0, stream>>>(x, W1, a_src1, a_dst1, h1, AS1, AD1);
  k_agg1<<<dim3(NN / 4, 4), 256, 0, stream>>>(rp, col, AS1, AD1, h1, b1, h1agg);

  k_gemm2<<<NN / 16, 256, 0, stream>>>(h1agg, W2, a_src2, a_dst2, h2, AS2, AD2);
  k_agg2<<<NN / 4, 256, 0, stream>>>(rp, col, AS2, AD2, h2, b2, h2agg);

  k_pairs<<<NP / 64, PB, 0, stream>>>(pairs, h2agg, Wp1, bp1, Wp2, bp2, out);
}

// Round 12
// 401.324 us; speedup vs baseline: 1.2652x; 1.2652x over previous
//
#include <hip/hip_runtime.h>

#define NN 20000      // nodes
#define NE 640000     // edges (without self loops)
#define NEE 660000    // edges + self loops
#define NP 200000     // drug pairs
#define NEG 0.2f      // leaky relu slope

// ---------------- CSR build ----------------
__global__ void k_hist(const int* __restrict__ ei, int* __restrict__ cnt) {
  int i = blockIdx.x * 256 + threadIdx.x;
  if (i >= NEE) return;
  int d = (i < NE) ? ei[NE + i] : (i - NE);
  atomicAdd(&cnt[d], 1);
}

__global__ __launch_bounds__(1024) void k_scan(const int* __restrict__ cnt, int* __restrict__ rp) {
  __shared__ int ps[1024];
  const int CH = 20;  // 1024*20 = 20480 >= 20000
  int t = threadIdx.x;
  int lo = t * CH, hi = lo + CH;
  if (hi > NN) hi = NN;
  if (lo > NN) lo = NN;
  int s = 0;
  for (int i = lo; i < hi; ++i) s += cnt[i];
  ps[t] = s;
  __syncthreads();
  for (int off = 1; off < 1024; off <<= 1) {
    int v = (t >= off) ? ps[t - off] : 0;
    __syncthreads();
    ps[t] += v;
    __syncthreads();
  }
  int run = (t > 0) ? ps[t - 1] : 0;
  for (int i = lo; i < hi; ++i) { rp[i] = run; run += cnt[i]; }
  if (t == 1023) rp[NN] = ps[1023];
}

__global__ void k_scatter(const int* __restrict__ ei, const int* __restrict__ rp,
                          int* __restrict__ cur, int* __restrict__ col) {
  int i = blockIdx.x * 256 + threadIdx.x;
  if (i >= NEE) return;
  int s, d;
  if (i < NE) { s = ei[i]; d = ei[NE + i]; } else { s = i - NE; d = s; }
  int pos = atomicAdd(&cur[d], 1);
  col[rp[d] + pos] = s;
}

// ---------------- GEMM1: h1 = x @ W1  [20000,256]x[256,256], + alphas ----------------
// h1 is stored HEAD-MAJOR: h1h[head][n][64] so each head's slice is a contiguous 5 MB.
__global__ __launch_bounds__(256) void k_gemm1(
    const float* __restrict__ x, const float* __restrict__ W1,
    const float* __restrict__ as1, const float* __restrict__ ad1,
    float* __restrict__ h1h, float* __restrict__ AS1, float* __restrict__ AD1) {
  __shared__ float xsT[256][20];  // [k][row], pad 20 keeps 16B row alignment
  int c = threadIdx.x;            // output col 0..255
  int base = blockIdx.x * 16;     // 16 rows per block
  for (int i = threadIdx.x; i < 16 * 256; i += 256) {
    int r = i >> 8, k = i & 255;
    xsT[k][r] = x[(base + r) * 256 + k];
  }
  __syncthreads();
  float acc[16];
#pragma unroll
  for (int r = 0; r < 16; ++r) acc[r] = 0.f;
#pragma unroll 2
  for (int k = 0; k < 256; ++k) {
    float wv = W1[k * 256 + c];
    const float4* xr = (const float4*)&xsT[k][0];
    float4 x0 = xr[0], x1 = xr[1], x2 = xr[2], x3 = xr[3];
    acc[0] += x0.x * wv; acc[1] += x0.y * wv; acc[2] += x0.z * wv; acc[3] += x0.w * wv;
    acc[4] += x1.x * wv; acc[5] += x1.y * wv; acc[6] += x1.z * wv; acc[7] += x1.w * wv;
    acc[8] += x2.x * wv; acc[9] += x2.y * wv; acc[10] += x2.z * wv; acc[11] += x2.w * wv;
    acc[12] += x3.x * wv; acc[13] += x3.y * wv; acc[14] += x3.z * wv; acc[15] += x3.w * wv;
  }
  int head = c >> 6, cc = c & 63;
  float asv = as1[c];  // flat [head][c&63] == c
  float adv = ad1[c];
#pragma unroll
  for (int r = 0; r < 16; ++r) {
    h1h[((size_t)head * NN + (base + r)) * 64 + cc] = acc[r];
    float vs = acc[r] * asv, vd = acc[r] * adv;
#pragma unroll
    for (int off = 32; off > 0; off >>= 1) {
      vs += __shfl_xor(vs, off);
      vd += __shfl_xor(vd, off);
    }
    if ((c & 63) == 0) {
      AS1[(base + r) * 4 + head] = vs;
      AD1[(base + r) * 4 + head] = vd;
    }
  }
}

// ---------------- GAT layer-1 aggregation, FUSED edge weights: 4 edges x 16 lanes --------
__global__ __launch_bounds__(256) void k_agg1(
    const int* __restrict__ rp, const int* __restrict__ col,
    const float* __restrict__ AS1, const float* __restrict__ AD1,
    const float* __restrict__ h1h, const float* __restrict__ b1,
    float* __restrict__ out) {
  int wave = threadIdx.x >> 6, lane = threadIdx.x & 63;
  int head = blockIdx.y;
  int n = blockIdx.x * 4 + wave;
  int g = lane >> 4, c4 = (lane & 15) * 4;
  int e0 = rp[n], e1 = rp[n + 1];
  const float* hs = h1h + (size_t)head * NN * 64;
  float adv = AD1[n * 4 + head];
  float ax = 0.f, ay = 0.f, az = 0.f, aw = 0.f, den = 0.f;
#pragma unroll 2
  for (int e = e0; e < e1; e += 4) {
    int ee = e + g;
    bool valid = ee < e1;
    int ec = valid ? ee : e1 - 1;
    int s = col[ec];
    float ev = AS1[s * 4 + head] + adv;
    ev = ev > 0.f ? ev : NEG * ev;
    float p = valid ? __expf(ev) : 0.f;
    float4 hv = *(const float4*)(hs + (size_t)s * 64 + c4);
    ax += p * hv.x; ay += p * hv.y; az += p * hv.z; aw += p * hv.w;
    den += p;
  }
  ax += __shfl_xor(ax, 16); ax += __shfl_xor(ax, 32);
  ay += __shfl_xor(ay, 16); ay += __shfl_xor(ay, 32);
  az += __shfl_xor(az, 16); az += __shfl_xor(az, 32);
  aw += __shfl_xor(aw, 16); aw += __shfl_xor(aw, 32);
  den += __shfl_xor(den, 16); den += __shfl_xor(den, 32);
  if (lane < 16) {
    float inv = 1.f / den;
    int cbase = head * 64 + c4;
    float4 bv = *(const float4*)(b1 + cbase);
    float4 o;
    o.x = ax * inv + bv.x; o.y = ay * inv + bv.y;
    o.z = az * inv + bv.z; o.w = aw * inv + bv.w;
    o.x = o.x > 0.f ? o.x : __expf(o.x) - 1.f;
    o.y = o.y > 0.f ? o.y : __expf(o.y) - 1.f;
    o.z = o.z > 0.f ? o.z : __expf(o.z) - 1.f;
    o.w = o.w > 0.f ? o.w : __expf(o.w) - 1.f;
    *(float4*)(out + (size_t)n * 256 + cbase) = o;
  }
}

// ---------------- GEMM2: h2 = h1act @ W2  [20000,256]x[256,64], + alphas ----------------
__global__ __launch_bounds__(256) void k_gemm2(
    const float* __restrict__ h1a, const float* __restrict__ W2,
    const float* __restrict__ as2, const float* __restrict__ ad2,
    float* __restrict__ h2, float* __restrict__ AS2, float* __restrict__ AD2) {
  __shared__ float xsT[256][20];
  int tid = threadIdx.x;
  int c = tid & 63, w = tid >> 6;  // wave w handles rows 4w..4w+3
  int base = blockIdx.x * 16;
  for (int i = tid; i < 16 * 256; i += 256) {
    int r = i >> 8, k = i & 255;
    xsT[k][r] = h1a[(base + r) * 256 + k];
  }
  __syncthreads();
  float acc[4] = {0.f, 0.f, 0.f, 0.f};
#pragma unroll 2
  for (int k = 0; k < 256; ++k) {
    float wv = W2[k * 64 + c];
    float4 xv = *(const float4*)&xsT[k][w * 4];
    acc[0] += xv.x * wv; acc[1] += xv.y * wv; acc[2] += xv.z * wv; acc[3] += xv.w * wv;
  }
  float asv = as2[c], adv = ad2[c];
#pragma unroll
  for (int rr = 0; rr < 4; ++rr) {
    int row = base + w * 4 + rr;
    h2[row * 64 + c] = acc[rr];
    float vs = acc[rr] * asv, vd = acc[rr] * adv;
#pragma unroll
    for (int off = 32; off > 0; off >>= 1) {
      vs += __shfl_xor(vs, off);
      vd += __shfl_xor(vd, off);
    }
    if (c == 0) { AS2[row] = vs; AD2[row] = vd; }
  }
}

// ---------------- GAT layer-2 aggregation, FUSED edge weights ----------------
__global__ __launch_bounds__(256) void k_agg2(
    const int* __restrict__ rp, const int* __restrict__ col,
    const float* __restrict__ AS2, const float* __restrict__ AD2,
    const float* __restrict__ h2, const float* __restrict__ b2,
    float* __restrict__ out) {
  int wave = threadIdx.x >> 6, lane = threadIdx.x & 63;
  int n = blockIdx.x * 4 + wave;
  int g = lane >> 4, c4 = (lane & 15) * 4;
  int e0 = rp[n], e1 = rp[n + 1];
  float adv = AD2[n];
  float ax = 0.f, ay = 0.f, az = 0.f, aw = 0.f, den = 0.f;
#pragma unroll 2
  for (int e = e0; e < e1; e += 4) {
    int ee = e + g;
    bool valid = ee < e1;
    int ec = valid ? ee : e1 - 1;
    int s = col[ec];
    float ev = AS2[s] + adv;
    ev = ev > 0.f ? ev : NEG * ev;
    float p = valid ? __expf(ev) : 0.f;
    float4 hv = *(const float4*)(h2 + (size_t)s * 64 + c4);
    ax += p * hv.x; ay += p * hv.y; az += p * hv.z; aw += p * hv.w;
    den += p;
  }
  ax += __shfl_xor(ax, 16); ax += __shfl_xor(ax, 32);
  ay += __shfl_xor(ay, 16); ay += __shfl_xor(ay, 32);
  az += __shfl_xor(az, 16); az += __shfl_xor(az, 32);
  aw += __shfl_xor(aw, 16); aw += __shfl_xor(aw, 32);
  den += __shfl_xor(den, 16); den += __shfl_xor(den, 32);
  if (lane < 16) {
    float inv = 1.f / den;
    float4 bv = *(const float4*)(b2 + c4);
    float4 o;
    o.x = ax * inv + bv.x; o.y = ay * inv + bv.y;
    o.z = az * inv + bv.z; o.w = aw * inv + bv.w;
    o.x = o.x > 0.f ? o.x : __expf(o.x) - 1.f;
    o.y = o.y > 0.f ? o.y : __expf(o.y) - 1.f;
    o.z = o.z > 0.f ? o.z : __expf(o.z) - 1.f;
    o.w = o.w > 0.f ? o.w : __expf(o.w) - 1.f;
    *(float4*)(out + (size_t)n * 64 + c4) = o;
  }
}

// ---------------- per-node pair-MLP layer-1 precompute ----------------
// Layer 1 of the pair MLP is linear in the concat: z_pre = h_i@Wp1_top + h_j@Wp1_bot.
// AB[n][c]: c<64 -> A[n][c] = h2a[n]@Wp1[0:64][c] + bp1[c];  c>=64 -> B[n][c-64] =
// h2a[n]@Wp1[64:128][c-64].  20000x64x128 GEMM (164 MFMA) replaces the per-pair
// 128x64 GEMM (2.6 GFMA over pairs).  gemm1-proven structure.
__global__ __launch_bounds__(128) void k_predot(
    const float* __restrict__ h2a, const float* __restrict__ Wp1,
    const float* __restrict__ bp1, float* __restrict__ AB) {
  __shared__ float xsT[64][20];   // [k][row], 16 rows, pad 20
  int c = threadIdx.x;            // 0..127
  int base = blockIdx.x * 16;
  for (int i = threadIdx.x; i < 16 * 64; i += 128) {
    int r = i >> 6, k = i & 63;
    xsT[k][r] = h2a[(size_t)(base + r) * 64 + k];
  }
  __syncthreads();
  int part = c >> 6, u = c & 63;
  float bv = (part == 0) ? bp1[u] : 0.f;
  float acc[16];
#pragma unroll
  for (int r = 0; r < 16; ++r) acc[r] = bv;
#pragma unroll 2
  for (int k = 0; k < 64; ++k) {
    float wv = Wp1[(size_t)(part * 64 + k) * 64 + u];  // coalesced per half-wave
    const float4* xr = (const float4*)&xsT[k][0];
    float4 x0 = xr[0], x1 = xr[1], x2 = xr[2], x3 = xr[3];
    acc[0] += x0.x * wv; acc[1] += x0.y * wv; acc[2] += x0.z * wv; acc[3] += x0.w * wv;
    acc[4] += x1.x * wv; acc[5] += x1.y * wv; acc[6] += x1.z * wv; acc[7] += x1.w * wv;
    acc[8] += x2.x * wv; acc[9] += x2.y * wv; acc[10] += x2.z * wv; acc[11] += x2.w * wv;
    acc[12] += x3.x * wv; acc[13] += x3.y * wv; acc[14] += x3.z * wv; acc[15] += x3.w * wv;
  }
#pragma unroll
  for (int r = 0; r < 16; ++r) AB[(size_t)(base + r) * 128 + c] = acc[r];
}

// ---------------- pair MLP v12: z = relu(A[pi]+B[pj]) gather + v6 layer 2 ----------------
// Layer 1 collapsed to 16 float4 gathers + 32 adds per thread (AB is 10 MB, L2/L3-hot).
// Layer 2 is v6's proven 100-us structure verbatim: wave hu -> 43 output cols,
// thread-uniform weights (readfirstlane'd hu, consecutive inner index -> batched
// s_load_dwordxN), zt[64][66] = 16.9 KB -> 9 blocks/CU residency.
#define PB 128

__global__ __launch_bounds__(PB, 4) void k_pairs(
    const int* __restrict__ pairs, const float* __restrict__ AB,
    const float* __restrict__ Wp2, const float* __restrict__ bp2,
    float* __restrict__ out) {
  __shared__ float zt[64][66];  // [t][pair]
  int tid = threadIdx.x;
  int pp = tid & 63;                                      // pair within block
  int hu = __builtin_amdgcn_readfirstlane(tid >> 6);      // wave id 0/1, provably uniform
  int p = blockIdx.x * 64 + pp;
  int pi = pairs[2 * p], pj = pairs[2 * p + 1];

  // ---- z half hu: z[hu*32+u] = relu(A[pi][hu*32+u] + B[pj][hu*32+u])   (bp1 folded in A)
  {
    const float4* ar = (const float4*)(AB + (size_t)pi * 128 + hu * 32);
    const float4* br = (const float4*)(AB + (size_t)pj * 128 + 64 + hu * 32);
#pragma unroll
    for (int m = 0; m < 8; ++m) {
      float4 a = ar[m], b = br[m];
      int u = hu * 32 + m * 4;
      zt[u][pp]     = fmaxf(a.x + b.x, 0.f);
      zt[u + 1][pp] = fmaxf(a.y + b.y, 0.f);
      zt[u + 2][pp] = fmaxf(a.z + b.z, 0.f);
      zt[u + 3][pp] = fmaxf(a.w + b.w, 0.f);
    }
  }
  __syncthreads();

  // ---- layer 2: out[p][hu*43+j] = bp2 + sum_t z[t]*Wp2[t][hu*43+j]
  {
    float acc2[43];
#pragma unroll
    for (int j = 0; j < 43; ++j) acc2[j] = bp2[hu * 43 + j];
#pragma unroll 2
    for (int t = 0; t < 64; ++t) {
      float zv = zt[t][pp];
#pragma unroll
      for (int j = 0; j < 43; ++j)
        acc2[j] += zv * Wp2[t * 86 + hu * 43 + j];  // uniform, j-consecutive
    }
#pragma unroll
    for (int j = 0; j < 43; ++j) out[(size_t)p * 86 + hu * 43 + j] = acc2[j];
  }
}

extern "C" void kernel_launch(void* const* d_in, const int* in_sizes, int n_in,
                              void* d_out, int out_size, void* d_ws, size_t ws_size,
                              hipStream_t stream) {
  (void)in_sizes; (void)n_in; (void)out_size; (void)ws_size;
  const float* x      = (const float*)d_in[0];
  const int*   ei     = (const int*)d_in[1];
  const int*   pairs  = (const int*)d_in[2];
  const float* W1     = (const float*)d_in[3];
  const float* a_src1 = (const float*)d_in[4];
  const float* a_dst1 = (const float*)d_in[5];
  const float* b1     = (const float*)d_in[6];
  const float* W2     = (const float*)d_in[7];
  const float* a_src2 = (const float*)d_in[8];
  const float* a_dst2 = (const float*)d_in[9];
  const float* b2     = (const float*)d_in[10];
  const float* Wp1    = (const float*)d_in[11];
  const float* bp1    = (const float*)d_in[12];
  const float* Wp2    = (const float*)d_in[13];
  const float* bp2    = (const float*)d_in[14];
  float* out = (float*)d_out;

  char* w = (char*)d_ws;
  auto alloc = [&](size_t bytes) -> void* {
    void* pp = (void*)w;
    w += (bytes + 255) & ~(size_t)255;
    return pp;
  };
  float* h1    = (float*)alloc((size_t)NN * 256 * 4);  // head-major [4][NN][64]
  float* AS1   = (float*)alloc((size_t)NN * 4 * 4);
  float* AD1   = (float*)alloc((size_t)NN * 4 * 4);
  float* h1agg = (float*)alloc((size_t)NN * 256 * 4);
  float* h2    = (float*)alloc((size_t)NN * 64 * 4);
  float* AS2   = (float*)alloc((size_t)NN * 4);
  float* AD2   = (float*)alloc((size_t)NN * 4);
  float* h2agg = (float*)alloc((size_t)NN * 64 * 4);
  float* AB    = (float*)alloc((size_t)NN * 128 * 4);
  int*   rp    = (int*)alloc((size_t)(NN + 1) * 4);
  int*   cnt   = (int*)alloc((size_t)NN * 4);
  int*   cur   = (int*)alloc((size_t)NN * 4);
  int*   col   = (int*)alloc((size_t)NEE * 4);

  hipMemsetAsync(cnt, 0, (size_t)NN * 4, stream);
  hipMemsetAsync(cur, 0, (size_t)NN * 4, stream);

  const int EB = (NEE + 255) / 256;  // 2579
  k_hist<<<EB, 256, 0, stream>>>(ei, cnt);
  k_scan<<<1, 1024, 0, stream>>>(cnt, rp);
  k_scatter<<<EB, 256, 0, stream>>>(ei, rp, cur, col);

  k_gemm1<<<NN / 16, 256, 0, stream>>>(x, W1, a_src1, a_dst1, h1, AS1, AD1);
  k_agg1<<<dim3(NN / 4, 4), 256, 0, stream>>>(rp, col, AS1, AD1, h1, b1, h1agg);

  k_gemm2<<<NN / 16, 256, 0, stream>>>(h1agg, W2, a_src2, a_dst2, h2, AS2, AD2);
  k_agg2<<<NN / 4, 256, 0, stream>>>(rp, col, AS2, AD2, h2, b2, h2agg);

  k_predot<<<NN / 16, 128, 0, stream>>>(h2agg, Wp1, bp1, AB);
  k_pairs<<<NP / 64, PB, 0, stream>>>(pairs, AB, Wp2, bp2, out);
}

// Round 13
// 388.700 us; speedup vs baseline: 1.3063x; 1.0325x over previous
//
#include <hip/hip_runtime.h>

#define NN 20000      // nodes
#define NE 640000     // edges (without self loops)
#define NEE 660000    // edges + self loops
#define NP 200000     // drug pairs
#define NEG 0.2f      // leaky relu slope

// ---------------- CSR build ----------------
__global__ void k_hist(const int* __restrict__ ei, int* __restrict__ cnt) {
  int i = blockIdx.x * 256 + threadIdx.x;
  if (i >= NEE) return;
  int d = (i < NE) ? ei[NE + i] : (i - NE);
  atomicAdd(&cnt[d], 1);
}

__global__ __launch_bounds__(1024) void k_scan(const int* __restrict__ cnt, int* __restrict__ rp) {
  __shared__ int ps[1024];
  const int CH = 20;  // 1024*20 = 20480 >= 20000
  int t = threadIdx.x;
  int lo = t * CH, hi = lo + CH;
  if (hi > NN) hi = NN;
  if (lo > NN) lo = NN;
  int s = 0;
  for (int i = lo; i < hi; ++i) s += cnt[i];
  ps[t] = s;
  __syncthreads();
  for (int off = 1; off < 1024; off <<= 1) {
    int v = (t >= off) ? ps[t - off] : 0;
    __syncthreads();
    ps[t] += v;
    __syncthreads();
  }
  int run = (t > 0) ? ps[t - 1] : 0;
  for (int i = lo; i < hi; ++i) { rp[i] = run; run += cnt[i]; }
  if (t == 1023) rp[NN] = ps[1023];
}

__global__ void k_scatter(const int* __restrict__ ei, const int* __restrict__ rp,
                          int* __restrict__ cur, int* __restrict__ col) {
  int i = blockIdx.x * 256 + threadIdx.x;
  if (i >= NEE) return;
  int s, d;
  if (i < NE) { s = ei[i]; d = ei[NE + i]; } else { s = i - NE; d = s; }
  int pos = atomicAdd(&cur[d], 1);
  col[rp[d] + pos] = s;
}

// ---------------- GEMM1: h1 = x @ W1  [20000,256]x[256,256], + alphas ----------------
// h1 is stored HEAD-MAJOR: h1h[head][n][64] so each head's slice is a contiguous 5 MB.
__global__ __launch_bounds__(256) void k_gemm1(
    const float* __restrict__ x, const float* __restrict__ W1,
    const float* __restrict__ as1, const float* __restrict__ ad1,
    float* __restrict__ h1h, float* __restrict__ AS1, float* __restrict__ AD1) {
  __shared__ float xsT[256][20];  // [k][row], pad 20 keeps 16B row alignment
  int c = threadIdx.x;            // output col 0..255
  int base = blockIdx.x * 16;     // 16 rows per block
  for (int i = threadIdx.x; i < 16 * 256; i += 256) {
    int r = i >> 8, k = i & 255;
    xsT[k][r] = x[(base + r) * 256 + k];
  }
  __syncthreads();
  float acc[16];
#pragma unroll
  for (int r = 0; r < 16; ++r) acc[r] = 0.f;
#pragma unroll 2
  for (int k = 0; k < 256; ++k) {
    float wv = W1[k * 256 + c];
    const float4* xr = (const float4*)&xsT[k][0];
    float4 x0 = xr[0], x1 = xr[1], x2 = xr[2], x3 = xr[3];
    acc[0] += x0.x * wv; acc[1] += x0.y * wv; acc[2] += x0.z * wv; acc[3] += x0.w * wv;
    acc[4] += x1.x * wv; acc[5] += x1.y * wv; acc[6] += x1.z * wv; acc[7] += x1.w * wv;
    acc[8] += x2.x * wv; acc[9] += x2.y * wv; acc[10] += x2.z * wv; acc[11] += x2.w * wv;
    acc[12] += x3.x * wv; acc[13] += x3.y * wv; acc[14] += x3.z * wv; acc[15] += x3.w * wv;
  }
  int head = c >> 6, cc = c & 63;
  float asv = as1[c];  // flat [head][c&63] == c
  float adv = ad1[c];
#pragma unroll
  for (int r = 0; r < 16; ++r) {
    h1h[((size_t)head * NN + (base + r)) * 64 + cc] = acc[r];
    float vs = acc[r] * asv, vd = acc[r] * adv;
#pragma unroll
    for (int off = 32; off > 0; off >>= 1) {
      vs += __shfl_xor(vs, off);
      vd += __shfl_xor(vd, off);
    }
    if ((c & 63) == 0) {
      AS1[(base + r) * 4 + head] = vs;
      AD1[(base + r) * 4 + head] = vd;
    }
  }
}

// ---------------- GAT layer-1 aggregation: XCD-pinned heads + pipelined loads ------------
// 1D grid of 20000 blocks. xcd = bid&7 (round-robin block->XCD mapping); head = xcd>>1
// so each XCD gathers from exactly ONE 5 MB head slice (~fits its 4 MB L2) instead of
// all four (20 MB working set -> the 151 MB HBM FETCH seen in round 12).
// col/AS1 of iteration i+1 are prefetched branch-free during iteration i (tail reads
// clamp to e1-1, always in-bounds) -> one memory latency per iteration instead of two.
__global__ __launch_bounds__(256, 4) void k_agg1(
    const int* __restrict__ rp, const int* __restrict__ col,
    const float* __restrict__ AS1, const float* __restrict__ AD1,
    const float* __restrict__ h1h, const float* __restrict__ b1,
    float* __restrict__ out) {
  int b = blockIdx.x;
  int xcd = b & 7;
  int head = xcd >> 1;
  int grp = (b >> 3) * 2 + (xcd & 1);      // 0..4999, bijective per head
  int wave = threadIdx.x >> 6, lane = threadIdx.x & 63;
  int n = grp * 4 + wave;
  int g = lane >> 4, c4 = (lane & 15) * 4;
  int e0 = rp[n], e1 = rp[n + 1];
  const float* hs = h1h + (size_t)head * NN * 64;
  float adv = AD1[n * 4 + head];
  float ax = 0.f, ay = 0.f, az = 0.f, aw = 0.f, den = 0.f;

  // prologue: load iteration 0's col + AS1
  int ee = e0 + g;
  bool v = ee < e1;
  int ec = v ? ee : e1 - 1;
  int s = col[ec];
  float asv = AS1[s * 4 + head];

  for (int e = e0; e < e1; e += 4) {
    // prefetch iteration i+1 (clamped: harmless in-bounds loads on the tail)
    int een = e + 4 + g;
    bool vn = een < e1;
    int ecn = vn ? een : e1 - 1;
    int sn = col[ecn];
    float asn = AS1[sn * 4 + head];
    // compute iteration i
    float ev = asv + adv;
    ev = ev > 0.f ? ev : NEG * ev;
    float p = v ? __expf(ev) : 0.f;
    float4 hv = *(const float4*)(hs + (size_t)s * 64 + c4);
    ax += p * hv.x; ay += p * hv.y; az += p * hv.z; aw += p * hv.w;
    den += p;
    s = sn; asv = asn; v = vn;
  }
  ax += __shfl_xor(ax, 16); ax += __shfl_xor(ax, 32);
  ay += __shfl_xor(ay, 16); ay += __shfl_xor(ay, 32);
  az += __shfl_xor(az, 16); az += __shfl_xor(az, 32);
  aw += __shfl_xor(aw, 16); aw += __shfl_xor(aw, 32);
  den += __shfl_xor(den, 16); den += __shfl_xor(den, 32);
  if (lane < 16) {
    float inv = 1.f / den;
    int cbase = head * 64 + c4;
    float4 bv = *(const float4*)(b1 + cbase);
    float4 o;
    o.x = ax * inv + bv.x; o.y = ay * inv + bv.y;
    o.z = az * inv + bv.z; o.w = aw * inv + bv.w;
    o.x = o.x > 0.f ? o.x : __expf(o.x) - 1.f;
    o.y = o.y > 0.f ? o.y : __expf(o.y) - 1.f;
    o.z = o.z > 0.f ? o.z : __expf(o.z) - 1.f;
    o.w = o.w > 0.f ? o.w : __expf(o.w) - 1.f;
    *(float4*)(out + (size_t)n * 256 + cbase) = o;
  }
}

// ---------------- GEMM2: h2 = h1act @ W2  [20000,256]x[256,64], + alphas ----------------
__global__ __launch_bounds__(256) void k_gemm2(
    const float* __restrict__ h1a, const float* __restrict__ W2,
    const float* __restrict__ as2, const float* __restrict__ ad2,
    float* __restrict__ h2, float* __restrict__ AS2, float* __restrict__ AD2) {
  __shared__ float xsT[256][20];
  int tid = threadIdx.x;
  int c = tid & 63, w = tid >> 6;  // wave w handles rows 4w..4w+3
  int base = blockIdx.x * 16;
  for (int i = tid; i < 16 * 256; i += 256) {
    int r = i >> 8, k = i & 255;
    xsT[k][r] = h1a[(base + r) * 256 + k];
  }
  __syncthreads();
  float acc[4] = {0.f, 0.f, 0.f, 0.f};
#pragma unroll 2
  for (int k = 0; k < 256; ++k) {
    float wv = W2[k * 64 + c];
    float4 xv = *(const float4*)&xsT[k][w * 4];
    acc[0] += xv.x * wv; acc[1] += xv.y * wv; acc[2] += xv.z * wv; acc[3] += xv.w * wv;
  }
  float asv = as2[c], adv = ad2[c];
#pragma unroll
  for (int rr = 0; rr < 4; ++rr) {
    int row = base + w * 4 + rr;
    h2[row * 64 + c] = acc[rr];
    float vs = acc[rr] * asv, vd = acc[rr] * adv;
#pragma unroll
    for (int off = 32; off > 0; off >>= 1) {
      vs += __shfl_xor(vs, off);
      vd += __shfl_xor(vd, off);
    }
    if (c == 0) { AS2[row] = vs; AD2[row] = vd; }
  }
}

// ---------------- GAT layer-2 aggregation, FUSED edge weights ----------------
__global__ __launch_bounds__(256) void k_agg2(
    const int* __restrict__ rp, const int* __restrict__ col,
    const float* __restrict__ AS2, const float* __restrict__ AD2,
    const float* __restrict__ h2, const float* __restrict__ b2,
    float* __restrict__ out) {
  int wave = threadIdx.x >> 6, lane = threadIdx.x & 63;
  int n = blockIdx.x * 4 + wave;
  int g = lane >> 4, c4 = (lane & 15) * 4;
  int e0 = rp[n], e1 = rp[n + 1];
  float adv = AD2[n];
  float ax = 0.f, ay = 0.f, az = 0.f, aw = 0.f, den = 0.f;
#pragma unroll 2
  for (int e = e0; e < e1; e += 4) {
    int ee = e + g;
    bool valid = ee < e1;
    int ec = valid ? ee : e1 - 1;
    int s = col[ec];
    float ev = AS2[s] + adv;
    ev = ev > 0.f ? ev : NEG * ev;
    float p = valid ? __expf(ev) : 0.f;
    float4 hv = *(const float4*)(h2 + (size_t)s * 64 + c4);
    ax += p * hv.x; ay += p * hv.y; az += p * hv.z; aw += p * hv.w;
    den += p;
  }
  ax += __shfl_xor(ax, 16); ax += __shfl_xor(ax, 32);
  ay += __shfl_xor(ay, 16); ay += __shfl_xor(ay, 32);
  az += __shfl_xor(az, 16); az += __shfl_xor(az, 32);
  aw += __shfl_xor(aw, 16); aw += __shfl_xor(aw, 32);
  den += __shfl_xor(den, 16); den += __shfl_xor(den, 32);
  if (lane < 16) {
    float inv = 1.f / den;
    float4 bv = *(const float4*)(b2 + c4);
    float4 o;
    o.x = ax * inv + bv.x; o.y = ay * inv + bv.y;
    o.z = az * inv + bv.z; o.w = aw * inv + bv.w;
    o.x = o.x > 0.f ? o.x : __expf(o.x) - 1.f;
    o.y = o.y > 0.f ? o.y : __expf(o.y) - 1.f;
    o.z = o.z > 0.f ? o.z : __expf(o.z) - 1.f;
    o.w = o.w > 0.f ? o.w : __expf(o.w) - 1.f;
    *(float4*)(out + (size_t)n * 64 + c4) = o;
  }
}

// ---------------- per-node pair-MLP layer-1 precompute ----------------
__global__ __launch_bounds__(128) void k_predot(
    const float* __restrict__ h2a, const float* __restrict__ Wp1,
    const float* __restrict__ bp1, float* __restrict__ AB) {
  __shared__ float xsT[64][20];   // [k][row], 16 rows, pad 20
  int c = threadIdx.x;            // 0..127
  int base = blockIdx.x * 16;
  for (int i = threadIdx.x; i < 16 * 64; i += 128) {
    int r = i >> 6, k = i & 63;
    xsT[k][r] = h2a[(size_t)(base + r) * 64 + k];
  }
  __syncthreads();
  int part = c >> 6, u = c & 63;
  float bv = (part == 0) ? bp1[u] : 0.f;
  float acc[16];
#pragma unroll
  for (int r = 0; r < 16; ++r) acc[r] = bv;
#pragma unroll 2
  for (int k = 0; k < 64; ++k) {
    float wv = Wp1[(size_t)(part * 64 + k) * 64 + u];  // coalesced per half-wave
    const float4* xr = (const float4*)&xsT[k][0];
    float4 x0 = xr[0], x1 = xr[1], x2 = xr[2], x3 = xr[3];
    acc[0] += x0.x * wv; acc[1] += x0.y * wv; acc[2] += x0.z * wv; acc[3] += x0.w * wv;
    acc[4] += x1.x * wv; acc[5] += x1.y * wv; acc[6] += x1.z * wv; acc[7] += x1.w * wv;
    acc[8] += x2.x * wv; acc[9] += x2.y * wv; acc[10] += x2.z * wv; acc[11] += x2.w * wv;
    acc[12] += x3.x * wv; acc[13] += x3.y * wv; acc[14] += x3.z * wv; acc[15] += x3.w * wv;
  }
#pragma unroll
  for (int r = 0; r < 16; ++r) AB[(size_t)(base + r) * 128 + c] = acc[r];
}

// ---------------- pair MLP v12: z = relu(A[pi]+B[pj]) gather + v6 layer 2 ----------------
#define PB 128

__global__ __launch_bounds__(PB, 4) void k_pairs(
    const int* __restrict__ pairs, const float* __restrict__ AB,
    const float* __restrict__ Wp2, const float* __restrict__ bp2,
    float* __restrict__ out) {
  __shared__ float zt[64][66];  // [t][pair]
  int tid = threadIdx.x;
  int pp = tid & 63;                                      // pair within block
  int hu = __builtin_amdgcn_readfirstlane(tid >> 6);      // wave id 0/1, provably uniform
  int p = blockIdx.x * 64 + pp;
  int pi = pairs[2 * p], pj = pairs[2 * p + 1];

  // ---- z half hu: z[hu*32+u] = relu(A[pi][hu*32+u] + B[pj][hu*32+u])   (bp1 folded in A)
  {
    const float4* ar = (const float4*)(AB + (size_t)pi * 128 + hu * 32);
    const float4* br = (const float4*)(AB + (size_t)pj * 128 + 64 + hu * 32);
#pragma unroll
    for (int m = 0; m < 8; ++m) {
      float4 a = ar[m], b = br[m];
      int u = hu * 32 + m * 4;
      zt[u][pp]     = fmaxf(a.x + b.x, 0.f);
      zt[u + 1][pp] = fmaxf(a.y + b.y, 0.f);
      zt[u + 2][pp] = fmaxf(a.z + b.z, 0.f);
      zt[u + 3][pp] = fmaxf(a.w + b.w, 0.f);
    }
  }
  __syncthreads();

  // ---- layer 2: out[p][hu*43+j] = bp2 + sum_t z[t]*Wp2[t][hu*43+j]
  {
    float acc2[43];
#pragma unroll
    for (int j = 0; j < 43; ++j) acc2[j] = bp2[hu * 43 + j];
#pragma unroll 2
    for (int t = 0; t < 64; ++t) {
      float zv = zt[t][pp];
#pragma unroll
      for (int j = 0; j < 43; ++j)
        acc2[j] += zv * Wp2[t * 86 + hu * 43 + j];  // uniform, j-consecutive
    }
#pragma unroll
    for (int j = 0; j < 43; ++j) out[(size_t)p * 86 + hu * 43 + j] = acc2[j];
  }
}

extern "C" void kernel_launch(void* const* d_in, const int* in_sizes, int n_in,
                              void* d_out, int out_size, void* d_ws, size_t ws_size,
                              hipStream_t stream) {
  (void)in_sizes; (void)n_in; (void)out_size; (void)ws_size;
  const float* x      = (const float*)d_in[0];
  const int*   ei     = (const int*)d_in[1];
  const int*   pairs  = (const int*)d_in[2];
  const float* W1     = (const float*)d_in[3];
  const float* a_src1 = (const float*)d_in[4];
  const float* a_dst1 = (const float*)d_in[5];
  const float* b1     = (const float*)d_in[6];
  const float* W2     = (const float*)d_in[7];
  const float* a_src2 = (const float*)d_in[8];
  const float* a_dst2 = (const float*)d_in[9];
  const float* b2     = (const float*)d_in[10];
  const float* Wp1    = (const float*)d_in[11];
  const float* bp1    = (const float*)d_in[12];
  const float* Wp2    = (const float*)d_in[13];
  const float* bp2    = (const float*)d_in[14];
  float* out = (float*)d_out;

  char* w = (char*)d_ws;
  auto alloc = [&](size_t bytes) -> void* {
    void* pp = (void*)w;
    w += (bytes + 255) & ~(size_t)255;
    return pp;
  };
  float* h1    = (float*)alloc((size_t)NN * 256 * 4);  // head-major [4][NN][64]
  float* AS1   = (float*)alloc((size_t)NN * 4 * 4);
  float* AD1   = (float*)alloc((size_t)NN * 4 * 4);
  float* h1agg = (float*)alloc((size_t)NN * 256 * 4);
  float* h2    = (float*)alloc((size_t)NN * 64 * 4);
  float* AS2   = (float*)alloc((size_t)NN * 4);
  float* AD2   = (float*)alloc((size_t)NN * 4);
  float* h2agg = (float*)alloc((size_t)NN * 64 * 4);
  float* AB    = (float*)alloc((size_t)NN * 128 * 4);
  int*   rp    = (int*)alloc((size_t)(NN + 1) * 4);
  int*   cnt   = (int*)alloc((size_t)NN * 4);
  int*   cur   = (int*)alloc((size_t)NN * 4);
  int*   col   = (int*)alloc((size_t)NEE * 4);

  hipMemsetAsync(cnt, 0, (size_t)NN * 4, stream);
  hipMemsetAsync(cur, 0, (size_t)NN * 4, stream);

  const int EB = (NEE + 255) / 256;  // 2579
  k_hist<<<EB, 256, 0, stream>>>(ei, cnt);
  k_scan<<<1, 1024, 0, stream>>>(cnt, rp);
  k_scatter<<<EB, 256, 0, stream>>>(ei, rp, cur, col);

  k_gemm1<<<NN / 16, 256, 0, stream>>>(x, W1, a_src1, a_dst1, h1, AS1, AD1);
  k_agg1<<<NN, 256, 0, stream>>>(rp, col, AS1, AD1, h1, b1, h1agg);

  k_gemm2<<<NN / 16, 256, 0, stream>>>(h1agg, W2, a_src2, a_dst2, h2, AS2, AD2);
  k_agg2<<<NN / 4, 256, 0, stream>>>(rp, col, AS2, AD2, h2, b2, h2agg);

  k_predot<<<NN / 16, 128, 0, stream>>>(h2agg, Wp1, bp1, AB);
  k_pairs<<<NP / 64, PB, 0, stream>>>(pairs, AB, Wp2, bp2, out);
}

// Round 14
// 359.798 us; speedup vs baseline: 1.4113x; 1.0803x over previous
//
#include <hip/hip_runtime.h>
#include <hip/hip_fp16.h>

#define NN 20000      // nodes
#define NE 640000     // edges (without self loops)
#define NEE 660000    // edges + self loops
#define NP 200000     // drug pairs
#define NEG 0.2f      // leaky relu slope

// ---------------- CSR build ----------------
__global__ void k_hist(const int* __restrict__ ei, int* __restrict__ cnt) {
  int i = blockIdx.x * 256 + threadIdx.x;
  if (i >= NEE) return;
  int d = (i < NE) ? ei[NE + i] : (i - NE);
  atomicAdd(&cnt[d], 1);
}

__global__ __launch_bounds__(1024) void k_scan(const int* __restrict__ cnt, int* __restrict__ rp) {
  __shared__ int ps[1024];
  const int CH = 20;  // 1024*20 = 20480 >= 20000
  int t = threadIdx.x;
  int lo = t * CH, hi = lo + CH;
  if (hi > NN) hi = NN;
  if (lo > NN) lo = NN;
  int s = 0;
  for (int i = lo; i < hi; ++i) s += cnt[i];
  ps[t] = s;
  __syncthreads();
  for (int off = 1; off < 1024; off <<= 1) {
    int v = (t >= off) ? ps[t - off] : 0;
    __syncthreads();
    ps[t] += v;
    __syncthreads();
  }
  int run = (t > 0) ? ps[t - 1] : 0;
  for (int i = lo; i < hi; ++i) { rp[i] = run; run += cnt[i]; }
  if (t == 1023) rp[NN] = ps[1023];
}

__global__ void k_scatter(const int* __restrict__ ei, const int* __restrict__ rp,
                          int* __restrict__ cur, int* __restrict__ col) {
  int i = blockIdx.x * 256 + threadIdx.x;
  if (i >= NEE) return;
  int s, d;
  if (i < NE) { s = ei[i]; d = ei[NE + i]; } else { s = i - NE; d = s; }
  int pos = atomicAdd(&cur[d], 1);
  col[rp[d] + pos] = s;
}

// ---------------- GEMM1: h1 = x @ W1, fp16 head-major store + alphas ----------------
// h1h16[head][n][64] in HALF: it is ONLY a gather source for k_agg1; fp16 halves the
// slice to 2.5 MB (< 4 MB XCD L2) and the gather bytes. Accumulation stays fp32.
__global__ __launch_bounds__(256) void k_gemm1(
    const float* __restrict__ x, const float* __restrict__ W1,
    const float* __restrict__ as1, const float* __restrict__ ad1,
    __half* __restrict__ h1h16, float* __restrict__ AS1, float* __restrict__ AD1) {
  __shared__ float xsT[256][20];  // [k][row], pad 20 keeps 16B row alignment
  int c = threadIdx.x;            // output col 0..255
  int base = blockIdx.x * 16;     // 16 rows per block
  for (int i = threadIdx.x; i < 16 * 256; i += 256) {
    int r = i >> 8, k = i & 255;
    xsT[k][r] = x[(base + r) * 256 + k];
  }
  __syncthreads();
  float acc[16];
#pragma unroll
  for (int r = 0; r < 16; ++r) acc[r] = 0.f;
#pragma unroll 2
  for (int k = 0; k < 256; ++k) {
    float wv = W1[k * 256 + c];
    const float4* xr = (const float4*)&xsT[k][0];
    float4 x0 = xr[0], x1 = xr[1], x2 = xr[2], x3 = xr[3];
    acc[0] += x0.x * wv; acc[1] += x0.y * wv; acc[2] += x0.z * wv; acc[3] += x0.w * wv;
    acc[4] += x1.x * wv; acc[5] += x1.y * wv; acc[6] += x1.z * wv; acc[7] += x1.w * wv;
    acc[8] += x2.x * wv; acc[9] += x2.y * wv; acc[10] += x2.z * wv; acc[11] += x2.w * wv;
    acc[12] += x3.x * wv; acc[13] += x3.y * wv; acc[14] += x3.z * wv; acc[15] += x3.w * wv;
  }
  int head = c >> 6, cc = c & 63;
  float asv = as1[c];  // flat [head][c&63] == c
  float adv = ad1[c];
#pragma unroll
  for (int r = 0; r < 16; ++r) {
    h1h16[((size_t)head * NN + (base + r)) * 64 + cc] = __float2half(acc[r]);
    float vs = acc[r] * asv, vd = acc[r] * adv;
#pragma unroll
    for (int off = 32; off > 0; off >>= 1) {
      vs += __shfl_xor(vs, off);
      vd += __shfl_xor(vd, off);
    }
    if ((c & 63) == 0) {
      AS1[(base + r) * 4 + head] = vs;
      AD1[(base + r) * 4 + head] = vd;
    }
  }
}

// ---------------- GAT layer-1 aggregation: XCD-pinned heads, fp16 gather, pipelined ------
__global__ __launch_bounds__(256, 4) void k_agg1(
    const int* __restrict__ rp, const int* __restrict__ col,
    const float* __restrict__ AS1, const float* __restrict__ AD1,
    const __half* __restrict__ h1h16, const float* __restrict__ b1,
    float* __restrict__ out) {
  int b = blockIdx.x;
  int xcd = b & 7;
  int head = xcd >> 1;
  int grp = (b >> 3) * 2 + (xcd & 1);      // 0..4999, bijective per head
  int wave = threadIdx.x >> 6, lane = threadIdx.x & 63;
  int n = grp * 4 + wave;
  int g = lane >> 4, c4 = (lane & 15) * 4;
  int e0 = rp[n], e1 = rp[n + 1];
  const __half* hs = h1h16 + (size_t)head * NN * 64;
  float adv = AD1[n * 4 + head];
  float ax = 0.f, ay = 0.f, az = 0.f, aw = 0.f, den = 0.f;

  // prologue: load iteration 0's col + AS1
  int ee = e0 + g;
  bool v = ee < e1;
  int ec = v ? ee : e1 - 1;
  int s = col[ec];
  float asv = AS1[s * 4 + head];

  for (int e = e0; e < e1; e += 4) {
    // prefetch iteration i+1 (clamped: harmless in-bounds loads on the tail)
    int een = e + 4 + g;
    bool vn = een < e1;
    int ecn = vn ? een : e1 - 1;
    int sn = col[ecn];
    float asn = AS1[sn * 4 + head];
    // compute iteration i
    float ev = asv + adv;
    ev = ev > 0.f ? ev : NEG * ev;
    float p = v ? __expf(ev) : 0.f;
    __half2 h01 = *(const __half2*)(hs + (size_t)s * 64 + c4);
    __half2 h23 = *(const __half2*)(hs + (size_t)s * 64 + c4 + 2);
    float2 f0 = __half22float2(h01), f1 = __half22float2(h23);
    ax += p * f0.x; ay += p * f0.y; az += p * f1.x; aw += p * f1.y;
    den += p;
    s = sn; asv = asn; v = vn;
  }
  ax += __shfl_xor(ax, 16); ax += __shfl_xor(ax, 32);
  ay += __shfl_xor(ay, 16); ay += __shfl_xor(ay, 32);
  az += __shfl_xor(az, 16); az += __shfl_xor(az, 32);
  aw += __shfl_xor(aw, 16); aw += __shfl_xor(aw, 32);
  den += __shfl_xor(den, 16); den += __shfl_xor(den, 32);
  if (lane < 16) {
    float inv = 1.f / den;
    int cbase = head * 64 + c4;
    float4 bv = *(const float4*)(b1 + cbase);
    float4 o;
    o.x = ax * inv + bv.x; o.y = ay * inv + bv.y;
    o.z = az * inv + bv.z; o.w = aw * inv + bv.w;
    o.x = o.x > 0.f ? o.x : __expf(o.x) - 1.f;
    o.y = o.y > 0.f ? o.y : __expf(o.y) - 1.f;
    o.z = o.z > 0.f ? o.z : __expf(o.z) - 1.f;
    o.w = o.w > 0.f ? o.w : __expf(o.w) - 1.f;
    *(float4*)(out + (size_t)n * 256 + cbase) = o;
  }
}

// ---------------- GEMM2: h2 = h1act @ W2, fp16 store (gather-only tensor) + alphas -------
__global__ __launch_bounds__(256) void k_gemm2(
    const float* __restrict__ h1a, const float* __restrict__ W2,
    const float* __restrict__ as2, const float* __restrict__ ad2,
    __half* __restrict__ h2h16, float* __restrict__ AS2, float* __restrict__ AD2) {
  __shared__ float xsT[256][20];
  int tid = threadIdx.x;
  int c = tid & 63, w = tid >> 6;  // wave w handles rows 4w..4w+3
  int base = blockIdx.x * 16;
  for (int i = tid; i < 16 * 256; i += 256) {
    int r = i >> 8, k = i & 255;
    xsT[k][r] = h1a[(base + r) * 256 + k];
  }
  __syncthreads();
  float acc[4] = {0.f, 0.f, 0.f, 0.f};
#pragma unroll 2
  for (int k = 0; k < 256; ++k) {
    float wv = W2[k * 64 + c];
    float4 xv = *(const float4*)&xsT[k][w * 4];
    acc[0] += xv.x * wv; acc[1] += xv.y * wv; acc[2] += xv.z * wv; acc[3] += xv.w * wv;
  }
  float asv = as2[c], adv = ad2[c];
#pragma unroll
  for (int rr = 0; rr < 4; ++rr) {
    int row = base + w * 4 + rr;
    h2h16[(size_t)row * 64 + c] = __float2half(acc[rr]);
    float vs = acc[rr] * asv, vd = acc[rr] * adv;
#pragma unroll
    for (int off = 32; off > 0; off >>= 1) {
      vs += __shfl_xor(vs, off);
      vd += __shfl_xor(vd, off);
    }
    if (c == 0) { AS2[row] = vs; AD2[row] = vd; }
  }
}

// ---------------- GAT layer-2 aggregation: fp16 gather + pipelined loads ----------------
__global__ __launch_bounds__(256, 4) void k_agg2(
    const int* __restrict__ rp, const int* __restrict__ col,
    const float* __restrict__ AS2, const float* __restrict__ AD2,
    const __half* __restrict__ h2h16, const float* __restrict__ b2,
    float* __restrict__ out) {
  int wave = threadIdx.x >> 6, lane = threadIdx.x & 63;
  int n = blockIdx.x * 4 + wave;
  int g = lane >> 4, c4 = (lane & 15) * 4;
  int e0 = rp[n], e1 = rp[n + 1];
  float adv = AD2[n];
  float ax = 0.f, ay = 0.f, az = 0.f, aw = 0.f, den = 0.f;

  int ee = e0 + g;
  bool v = ee < e1;
  int ec = v ? ee : e1 - 1;
  int s = col[ec];
  float asv = AS2[s];

  for (int e = e0; e < e1; e += 4) {
    int een = e + 4 + g;
    bool vn = een < e1;
    int ecn = vn ? een : e1 - 1;
    int sn = col[ecn];
    float asn = AS2[sn];
    float ev = asv + adv;
    ev = ev > 0.f ? ev : NEG * ev;
    float p = v ? __expf(ev) : 0.f;
    __half2 h01 = *(const __half2*)(h2h16 + (size_t)s * 64 + c4);
    __half2 h23 = *(const __half2*)(h2h16 + (size_t)s * 64 + c4 + 2);
    float2 f0 = __half22float2(h01), f1 = __half22float2(h23);
    ax += p * f0.x; ay += p * f0.y; az += p * f1.x; aw += p * f1.y;
    den += p;
    s = sn; asv = asn; v = vn;
  }
  ax += __shfl_xor(ax, 16); ax += __shfl_xor(ax, 32);
  ay += __shfl_xor(ay, 16); ay += __shfl_xor(ay, 32);
  az += __shfl_xor(az, 16); az += __shfl_xor(az, 32);
  aw += __shfl_xor(aw, 16); aw += __shfl_xor(aw, 32);
  den += __shfl_xor(den, 16); den += __shfl_xor(den, 32);
  if (lane < 16) {
    float inv = 1.f / den;
    float4 bv = *(const float4*)(b2 + c4);
    float4 o;
    o.x = ax * inv + bv.x; o.y = ay * inv + bv.y;
    o.z = az * inv + bv.z; o.w = aw * inv + bv.w;
    o.x = o.x > 0.f ? o.x : __expf(o.x) - 1.f;
    o.y = o.y > 0.f ? o.y : __expf(o.y) - 1.f;
    o.z = o.z > 0.f ? o.z : __expf(o.z) - 1.f;
    o.w = o.w > 0.f ? o.w : __expf(o.w) - 1.f;
    *(float4*)(out + (size_t)n * 64 + c4) = o;
  }
}

// ---------------- per-node pair-MLP layer-1 precompute ----------------
__global__ __launch_bounds__(128) void k_predot(
    const float* __restrict__ h2a, const float* __restrict__ Wp1,
    const float* __restrict__ bp1, float* __restrict__ AB) {
  __shared__ float xsT[64][20];   // [k][row], 16 rows, pad 20
  int c = threadIdx.x;            // 0..127
  int base = blockIdx.x * 16;
  for (int i = threadIdx.x; i < 16 * 64; i += 128) {
    int r = i >> 6, k = i & 63;
    xsT[k][r] = h2a[(size_t)(base + r) * 64 + k];
  }
  __syncthreads();
  int part = c >> 6, u = c & 63;
  float bv = (part == 0) ? bp1[u] : 0.f;
  float acc[16];
#pragma unroll
  for (int r = 0; r < 16; ++r) acc[r] = bv;
#pragma unroll 2
  for (int k = 0; k < 64; ++k) {
    float wv = Wp1[(size_t)(part * 64 + k) * 64 + u];  // coalesced per half-wave
    const float4* xr = (const float4*)&xsT[k][0];
    float4 x0 = xr[0], x1 = xr[1], x2 = xr[2], x3 = xr[3];
    acc[0] += x0.x * wv; acc[1] += x0.y * wv; acc[2] += x0.z * wv; acc[3] += x0.w * wv;
    acc[4] += x1.x * wv; acc[5] += x1.y * wv; acc[6] += x1.z * wv; acc[7] += x1.w * wv;
    acc[8] += x2.x * wv; acc[9] += x2.y * wv; acc[10] += x2.z * wv; acc[11] += x2.w * wv;
    acc[12] += x3.x * wv; acc[13] += x3.y * wv; acc[14] += x3.z * wv; acc[15] += x3.w * wv;
  }
#pragma unroll
  for (int r = 0; r < 16; ++r) AB[(size_t)(base + r) * 128 + c] = acc[r];
}

// ---------------- pair MLP v12: z = relu(A[pi]+B[pj]) gather + v6 layer 2 ----------------
#define PB 128

__global__ __launch_bounds__(PB, 4) void k_pairs(
    const int* __restrict__ pairs, const float* __restrict__ AB,
    const float* __restrict__ Wp2, const float* __restrict__ bp2,
    float* __restrict__ out) {
  __shared__ float zt[64][66];  // [t][pair]
  int tid = threadIdx.x;
  int pp = tid & 63;                                      // pair within block
  int hu = __builtin_amdgcn_readfirstlane(tid >> 6);      // wave id 0/1, provably uniform
  int p = blockIdx.x * 64 + pp;
  int pi = pairs[2 * p], pj = pairs[2 * p + 1];

  // ---- z half hu: z[hu*32+u] = relu(A[pi][hu*32+u] + B[pj][hu*32+u])   (bp1 folded in A)
  {
    const float4* ar = (const float4*)(AB + (size_t)pi * 128 + hu * 32);
    const float4* br = (const float4*)(AB + (size_t)pj * 128 + 64 + hu * 32);
#pragma unroll
    for (int m = 0; m < 8; ++m) {
      float4 a = ar[m], b = br[m];
      int u = hu * 32 + m * 4;
      zt[u][pp]     = fmaxf(a.x + b.x, 0.f);
      zt[u + 1][pp] = fmaxf(a.y + b.y, 0.f);
      zt[u + 2][pp] = fmaxf(a.z + b.z, 0.f);
      zt[u + 3][pp] = fmaxf(a.w + b.w, 0.f);
    }
  }
  __syncthreads();

  // ---- layer 2: out[p][hu*43+j] = bp2 + sum_t z[t]*Wp2[t][hu*43+j]
  {
    float acc2[43];
#pragma unroll
    for (int j = 0; j < 43; ++j) acc2[j] = bp2[hu * 43 + j];
#pragma unroll 2
    for (int t = 0; t < 64; ++t) {
      float zv = zt[t][pp];
#pragma unroll
      for (int j = 0; j < 43; ++j)
        acc2[j] += zv * Wp2[t * 86 + hu * 43 + j];  // uniform, j-consecutive
    }
#pragma unroll
    for (int j = 0; j < 43; ++j) out[(size_t)p * 86 + hu * 43 + j] = acc2[j];
  }
}

extern "C" void kernel_launch(void* const* d_in, const int* in_sizes, int n_in,
                              void* d_out, int out_size, void* d_ws, size_t ws_size,
                              hipStream_t stream) {
  (void)in_sizes; (void)n_in; (void)out_size; (void)ws_size;
  const float* x      = (const float*)d_in[0];
  const int*   ei     = (const int*)d_in[1];
  const int*   pairs  = (const int*)d_in[2];
  const float* W1     = (const float*)d_in[3];
  const float* a_src1 = (const float*)d_in[4];
  const float* a_dst1 = (const float*)d_in[5];
  const float* b1     = (const float*)d_in[6];
  const float* W2     = (const float*)d_in[7];
  const float* a_src2 = (const float*)d_in[8];
  const float* a_dst2 = (const float*)d_in[9];
  const float* b2     = (const float*)d_in[10];
  const float* Wp1    = (const float*)d_in[11];
  const float* bp1    = (const float*)d_in[12];
  const float* Wp2    = (const float*)d_in[13];
  const float* bp2    = (const float*)d_in[14];
  float* out = (float*)d_out;

  char* w = (char*)d_ws;
  auto alloc = [&](size_t bytes) -> void* {
    void* pp = (void*)w;
    w += (bytes + 255) & ~(size_t)255;
    return pp;
  };
  __half* h1h16 = (__half*)alloc((size_t)NN * 256 * 2);  // head-major [4][NN][64] fp16
  float*  AS1   = (float*)alloc((size_t)NN * 4 * 4);
  float*  AD1   = (float*)alloc((size_t)NN * 4 * 4);
  float*  h1agg = (float*)alloc((size_t)NN * 256 * 4);
  __half* h2h16 = (__half*)alloc((size_t)NN * 64 * 2);   // fp16 gather copy
  float*  AS2   = (float*)alloc((size_t)NN * 4);
  float*  AD2   = (float*)alloc((size_t)NN * 4);
  float*  h2agg = (float*)alloc((size_t)NN * 64 * 4);
  float*  AB    = (float*)alloc((size_t)NN * 128 * 4);
  int*    rp    = (int*)alloc((size_t)(NN + 1) * 4);
  int*    cnt   = (int*)alloc((size_t)NN * 4);
  int*    cur   = (int*)alloc((size_t)NN * 4);
  int*    col   = (int*)alloc((size_t)NEE * 4);

  hipMemsetAsync(cnt, 0, (size_t)NN * 4, stream);
  hipMemsetAsync(cur, 0, (size_t)NN * 4, stream);

  const int EB = (NEE + 255) / 256;  // 2579
  k_hist<<<EB, 256, 0, stream>>>(ei, cnt);
  k_scan<<<1, 1024, 0, stream>>>(cnt, rp);
  k_scatter<<<EB, 256, 0, stream>>>(ei, rp, cur, col);

  k_gemm1<<<NN / 16, 256, 0, stream>>>(x, W1, a_src1, a_dst1, h1h16, AS1, AD1);
  k_agg1<<<NN, 256, 0, stream>>>(rp, col, AS1, AD1, h1h16, b1, h1agg);

  k_gemm2<<<NN / 16, 256, 0, stream>>>(h1agg, W2, a_src2, a_dst2, h2h16, AS2, AD2);
  k_agg2<<<NN / 4, 256, 0, stream>>>(rp, col, AS2, AD2, h2h16, b2, h2agg);

  k_predot<<<NN / 16, 128, 0, stream>>>(h2agg, Wp1, bp1, AB);
  k_pairs<<<NP / 64, PB, 0, stream>>>(pairs, AB, Wp2, bp2, out);
}

// Round 15
// 356.159 us; speedup vs baseline: 1.4257x; 1.0102x over previous
//
#include <hip/hip_runtime.h>
#include <hip/hip_fp16.h>

#define NN 20000      // nodes
#define NE 640000     // edges (without self loops)
#define NEE 660000    // edges + self loops
#define NP 200000     // drug pairs
#define NEG 0.2f      // leaky relu slope

// ---------------- CSR build ----------------
__global__ void k_hist(const int* __restrict__ ei, int* __restrict__ cnt) {
  int i = blockIdx.x * 256 + threadIdx.x;
  if (i >= NEE) return;
  int d = (i < NE) ? ei[NE + i] : (i - NE);
  atomicAdd(&cnt[d], 1);
}

__global__ __launch_bounds__(1024) void k_scan(const int* __restrict__ cnt, int* __restrict__ rp) {
  __shared__ int ps[1024];
  const int CH = 20;  // 1024*20 = 20480 >= 20000
  int t = threadIdx.x;
  int lo = t * CH, hi = lo + CH;
  if (hi > NN) hi = NN;
  if (lo > NN) lo = NN;
  int s = 0;
  for (int i = lo; i < hi; ++i) s += cnt[i];
  ps[t] = s;
  __syncthreads();
  for (int off = 1; off < 1024; off <<= 1) {
    int v = (t >= off) ? ps[t - off] : 0;
    __syncthreads();
    ps[t] += v;
    __syncthreads();
  }
  int run = (t > 0) ? ps[t - 1] : 0;
  for (int i = lo; i < hi; ++i) { rp[i] = run; run += cnt[i]; }
  if (t == 1023) rp[NN] = ps[1023];
}

__global__ void k_scatter(const int* __restrict__ ei, const int* __restrict__ rp,
                          int* __restrict__ cur, int* __restrict__ col) {
  int i = blockIdx.x * 256 + threadIdx.x;
  if (i >= NEE) return;
  int s, d;
  if (i < NE) { s = ei[i]; d = ei[NE + i]; } else { s = i - NE; d = s; }
  int pos = atomicAdd(&cur[d], 1);
  col[rp[d] + pos] = s;
}

// ---------------- GEMM1 v2: 128 threads, 2 cols/thread -> 32 FMA per 4 LDS reads --------
// Round-14 diagnosis: VGPR=28 < ~34 live serializes ds_read->FMA chains (VALU 27%).
// 2 output cols per thread doubles FMA per broadcast x-read; half the waves issue
// half the LDS traffic for the same 16x256 tile. launch_bounds(128,2) caps VGPR at
// 256 so ~52 live regs fit with prefetch slack. h1 stored fp16 head-major (gather-only).
__global__ __launch_bounds__(128, 2) void k_gemm1(
    const float* __restrict__ x, const float* __restrict__ W1,
    const float* __restrict__ as1, const float* __restrict__ ad1,
    __half* __restrict__ h1h16, float* __restrict__ AS1, float* __restrict__ AD1) {
  __shared__ float xsT[256][20];  // [k][row], pad 20 keeps 16B row alignment
  int tid = threadIdx.x;          // 0..127; cols (tid, tid+128)
  int base = blockIdx.x * 16;     // 16 rows per block
  for (int i = tid; i < 16 * 256; i += 128) {
    int r = i >> 8, k = i & 255;
    xsT[k][r] = x[(base + r) * 256 + k];
  }
  __syncthreads();
  float acc0[16], acc1[16];
#pragma unroll
  for (int r = 0; r < 16; ++r) { acc0[r] = 0.f; acc1[r] = 0.f; }
#pragma unroll 2
  for (int k = 0; k < 256; ++k) {
    float wv0 = W1[k * 256 + tid];
    float wv1 = W1[k * 256 + tid + 128];
    const float4* xr = (const float4*)&xsT[k][0];
    float4 x0 = xr[0], x1 = xr[1], x2 = xr[2], x3 = xr[3];
    acc0[0] += x0.x * wv0; acc0[1] += x0.y * wv0; acc0[2] += x0.z * wv0; acc0[3] += x0.w * wv0;
    acc0[4] += x1.x * wv0; acc0[5] += x1.y * wv0; acc0[6] += x1.z * wv0; acc0[7] += x1.w * wv0;
    acc0[8] += x2.x * wv0; acc0[9] += x2.y * wv0; acc0[10] += x2.z * wv0; acc0[11] += x2.w * wv0;
    acc0[12] += x3.x * wv0; acc0[13] += x3.y * wv0; acc0[14] += x3.z * wv0; acc0[15] += x3.w * wv0;
    acc1[0] += x0.x * wv1; acc1[1] += x0.y * wv1; acc1[2] += x0.z * wv1; acc1[3] += x0.w * wv1;
    acc1[4] += x1.x * wv1; acc1[5] += x1.y * wv1; acc1[6] += x1.z * wv1; acc1[7] += x1.w * wv1;
    acc1[8] += x2.x * wv1; acc1[9] += x2.y * wv1; acc1[10] += x2.z * wv1; acc1[11] += x2.w * wv1;
    acc1[12] += x3.x * wv1; acc1[13] += x3.y * wv1; acc1[14] += x3.z * wv1; acc1[15] += x3.w * wv1;
  }
  int c0 = tid, c1 = tid + 128;
  int head0 = c0 >> 6, cc0 = c0 & 63;   // wave0 -> head0=0, wave1 -> head0=1 (wave-uniform)
  int head1 = c1 >> 6, cc1 = c1 & 63;   // wave0 -> head1=2, wave1 -> head1=3
  float sA0 = as1[c0], dA0 = ad1[c0];
  float sA1 = as1[c1], dA1 = ad1[c1];
#pragma unroll
  for (int r = 0; r < 16; ++r) {
    h1h16[((size_t)head0 * NN + (base + r)) * 64 + cc0] = __float2half(acc0[r]);
    h1h16[((size_t)head1 * NN + (base + r)) * 64 + cc1] = __float2half(acc1[r]);
    float vs0 = acc0[r] * sA0, vd0 = acc0[r] * dA0;
    float vs1 = acc1[r] * sA1, vd1 = acc1[r] * dA1;
#pragma unroll
    for (int off = 32; off > 0; off >>= 1) {
      vs0 += __shfl_xor(vs0, off);
      vd0 += __shfl_xor(vd0, off);
      vs1 += __shfl_xor(vs1, off);
      vd1 += __shfl_xor(vd1, off);
    }
    if ((tid & 63) == 0) {
      AS1[(base + r) * 4 + head0] = vs0;
      AD1[(base + r) * 4 + head0] = vd0;
      AS1[(base + r) * 4 + head1] = vs1;
      AD1[(base + r) * 4 + head1] = vd1;
    }
  }
}

// ---------------- GAT layer-1 aggregation: XCD-pinned heads, fp16 gather, pipelined ------
__global__ __launch_bounds__(256, 4) void k_agg1(
    const int* __restrict__ rp, const int* __restrict__ col,
    const float* __restrict__ AS1, const float* __restrict__ AD1,
    const __half* __restrict__ h1h16, const float* __restrict__ b1,
    float* __restrict__ out) {
  int b = blockIdx.x;
  int xcd = b & 7;
  int head = xcd >> 1;
  int grp = (b >> 3) * 2 + (xcd & 1);      // 0..4999, bijective per head
  int wave = threadIdx.x >> 6, lane = threadIdx.x & 63;
  int n = grp * 4 + wave;
  int g = lane >> 4, c4 = (lane & 15) * 4;
  int e0 = rp[n], e1 = rp[n + 1];
  const __half* hs = h1h16 + (size_t)head * NN * 64;
  float adv = AD1[n * 4 + head];
  float ax = 0.f, ay = 0.f, az = 0.f, aw = 0.f, den = 0.f;

  // prologue: load iteration 0's col + AS1
  int ee = e0 + g;
  bool v = ee < e1;
  int ec = v ? ee : e1 - 1;
  int s = col[ec];
  float asv = AS1[s * 4 + head];

  for (int e = e0; e < e1; e += 4) {
    // prefetch iteration i+1 (clamped: harmless in-bounds loads on the tail)
    int een = e + 4 + g;
    bool vn = een < e1;
    int ecn = vn ? een : e1 - 1;
    int sn = col[ecn];
    float asn = AS1[sn * 4 + head];
    // compute iteration i
    float ev = asv + adv;
    ev = ev > 0.f ? ev : NEG * ev;
    float p = v ? __expf(ev) : 0.f;
    __half2 h01 = *(const __half2*)(hs + (size_t)s * 64 + c4);
    __half2 h23 = *(const __half2*)(hs + (size_t)s * 64 + c4 + 2);
    float2 f0 = __half22float2(h01), f1 = __half22float2(h23);
    ax += p * f0.x; ay += p * f0.y; az += p * f1.x; aw += p * f1.y;
    den += p;
    s = sn; asv = asn; v = vn;
  }
  ax += __shfl_xor(ax, 16); ax += __shfl_xor(ax, 32);
  ay += __shfl_xor(ay, 16); ay += __shfl_xor(ay, 32);
  az += __shfl_xor(az, 16); az += __shfl_xor(az, 32);
  aw += __shfl_xor(aw, 16); aw += __shfl_xor(aw, 32);
  den += __shfl_xor(den, 16); den += __shfl_xor(den, 32);
  if (lane < 16) {
    float inv = 1.f / den;
    int cbase = head * 64 + c4;
    float4 bv = *(const float4*)(b1 + cbase);
    float4 o;
    o.x = ax * inv + bv.x; o.y = ay * inv + bv.y;
    o.z = az * inv + bv.z; o.w = aw * inv + bv.w;
    o.x = o.x > 0.f ? o.x : __expf(o.x) - 1.f;
    o.y = o.y > 0.f ? o.y : __expf(o.y) - 1.f;
    o.z = o.z > 0.f ? o.z : __expf(o.z) - 1.f;
    o.w = o.w > 0.f ? o.w : __expf(o.w) - 1.f;
    *(float4*)(out + (size_t)n * 256 + cbase) = o;
  }
}

// ---------------- GEMM2: h2 = h1act @ W2, fp16 store (gather-only tensor) + alphas -------
__global__ __launch_bounds__(256) void k_gemm2(
    const float* __restrict__ h1a, const float* __restrict__ W2,
    const float* __restrict__ as2, const float* __restrict__ ad2,
    __half* __restrict__ h2h16, float* __restrict__ AS2, float* __restrict__ AD2) {
  __shared__ float xsT[256][20];
  int tid = threadIdx.x;
  int c = tid & 63, w = tid >> 6;  // wave w handles rows 4w..4w+3
  int base = blockIdx.x * 16;
  for (int i = tid; i < 16 * 256; i += 256) {
    int r = i >> 8, k = i & 255;
    xsT[k][r] = h1a[(base + r) * 256 + k];
  }
  __syncthreads();
  float acc[4] = {0.f, 0.f, 0.f, 0.f};
#pragma unroll 2
  for (int k = 0; k < 256; ++k) {
    float wv = W2[k * 64 + c];
    float4 xv = *(const float4*)&xsT[k][w * 4];
    acc[0] += xv.x * wv; acc[1] += xv.y * wv; acc[2] += xv.z * wv; acc[3] += xv.w * wv;
  }
  float asv = as2[c], adv = ad2[c];
#pragma unroll
  for (int rr = 0; rr < 4; ++rr) {
    int row = base + w * 4 + rr;
    h2h16[(size_t)row * 64 + c] = __float2half(acc[rr]);
    float vs = acc[rr] * asv, vd = acc[rr] * adv;
#pragma unroll
    for (int off = 32; off > 0; off >>= 1) {
      vs += __shfl_xor(vs, off);
      vd += __shfl_xor(vd, off);
    }
    if (c == 0) { AS2[row] = vs; AD2[row] = vd; }
  }
}

// ---------------- GAT layer-2 aggregation: fp16 gather + pipelined loads ----------------
__global__ __launch_bounds__(256, 4) void k_agg2(
    const int* __restrict__ rp, const int* __restrict__ col,
    const float* __restrict__ AS2, const float* __restrict__ AD2,
    const __half* __restrict__ h2h16, const float* __restrict__ b2,
    float* __restrict__ out) {
  int wave = threadIdx.x >> 6, lane = threadIdx.x & 63;
  int n = blockIdx.x * 4 + wave;
  int g = lane >> 4, c4 = (lane & 15) * 4;
  int e0 = rp[n], e1 = rp[n + 1];
  float adv = AD2[n];
  float ax = 0.f, ay = 0.f, az = 0.f, aw = 0.f, den = 0.f;

  int ee = e0 + g;
  bool v = ee < e1;
  int ec = v ? ee : e1 - 1;
  int s = col[ec];
  float asv = AS2[s];

  for (int e = e0; e < e1; e += 4) {
    int een = e + 4 + g;
    bool vn = een < e1;
    int ecn = vn ? een : e1 - 1;
    int sn = col[ecn];
    float asn = AS2[sn];
    float ev = asv + adv;
    ev = ev > 0.f ? ev : NEG * ev;
    float p = v ? __expf(ev) : 0.f;
    __half2 h01 = *(const __half2*)(h2h16 + (size_t)s * 64 + c4);
    __half2 h23 = *(const __half2*)(h2h16 + (size_t)s * 64 + c4 + 2);
    float2 f0 = __half22float2(h01), f1 = __half22float2(h23);
    ax += p * f0.x; ay += p * f0.y; az += p * f1.x; aw += p * f1.y;
    den += p;
    s = sn; asv = asn; v = vn;
  }
  ax += __shfl_xor(ax, 16); ax += __shfl_xor(ax, 32);
  ay += __shfl_xor(ay, 16); ay += __shfl_xor(ay, 32);
  az += __shfl_xor(az, 16); az += __shfl_xor(az, 32);
  aw += __shfl_xor(aw, 16); aw += __shfl_xor(aw, 32);
  den += __shfl_xor(den, 16); den += __shfl_xor(den, 32);
  if (lane < 16) {
    float inv = 1.f / den;
    float4 bv = *(const float4*)(b2 + c4);
    float4 o;
    o.x = ax * inv + bv.x; o.y = ay * inv + bv.y;
    o.z = az * inv + bv.z; o.w = aw * inv + bv.w;
    o.x = o.x > 0.f ? o.x : __expf(o.x) - 1.f;
    o.y = o.y > 0.f ? o.y : __expf(o.y) - 1.f;
    o.z = o.z > 0.f ? o.z : __expf(o.z) - 1.f;
    o.w = o.w > 0.f ? o.w : __expf(o.w) - 1.f;
    *(float4*)(out + (size_t)n * 64 + c4) = o;
  }
}

// ---------------- per-node pair-MLP layer-1 precompute ----------------
__global__ __launch_bounds__(128) void k_predot(
    const float* __restrict__ h2a, const float* __restrict__ Wp1,
    const float* __restrict__ bp1, float* __restrict__ AB) {
  __shared__ float xsT[64][20];   // [k][row], 16 rows, pad 20
  int c = threadIdx.x;            // 0..127
  int base = blockIdx.x * 16;
  for (int i = threadIdx.x; i < 16 * 64; i += 128) {
    int r = i >> 6, k = i & 63;
    xsT[k][r] = h2a[(size_t)(base + r) * 64 + k];
  }
  __syncthreads();
  int part = c >> 6, u = c & 63;
  float bv = (part == 0) ? bp1[u] : 0.f;
  float acc[16];
#pragma unroll
  for (int r = 0; r < 16; ++r) acc[r] = bv;
#pragma unroll 2
  for (int k = 0; k < 64; ++k) {
    float wv = Wp1[(size_t)(part * 64 + k) * 64 + u];  // coalesced per half-wave
    const float4* xr = (const float4*)&xsT[k][0];
    float4 x0 = xr[0], x1 = xr[1], x2 = xr[2], x3 = xr[3];
    acc[0] += x0.x * wv; acc[1] += x0.y * wv; acc[2] += x0.z * wv; acc[3] += x0.w * wv;
    acc[4] += x1.x * wv; acc[5] += x1.y * wv; acc[6] += x1.z * wv; acc[7] += x1.w * wv;
    acc[8] += x2.x * wv; acc[9] += x2.y * wv; acc[10] += x2.z * wv; acc[11] += x2.w * wv;
    acc[12] += x3.x * wv; acc[13] += x3.y * wv; acc[14] += x3.z * wv; acc[15] += x3.w * wv;
  }
#pragma unroll
  for (int r = 0; r < 16; ++r) AB[(size_t)(base + r) * 128 + c] = acc[r];
}

// ---------------- pair MLP v12: z = relu(A[pi]+B[pj]) gather + v6 layer 2 ----------------
#define PB 128

__global__ __launch_bounds__(PB, 4) void k_pairs(
    const int* __restrict__ pairs, const float* __restrict__ AB,
    const float* __restrict__ Wp2, const float* __restrict__ bp2,
    float* __restrict__ out) {
  __shared__ float zt[64][66];  // [t][pair]
  int tid = threadIdx.x;
  int pp = tid & 63;                                      // pair within block
  int hu = __builtin_amdgcn_readfirstlane(tid >> 6);      // wave id 0/1, provably uniform
  int p = blockIdx.x * 64 + pp;
  int pi = pairs[2 * p], pj = pairs[2 * p + 1];

  // ---- z half hu: z[hu*32+u] = relu(A[pi][hu*32+u] + B[pj][hu*32+u])   (bp1 folded in A)
  {
    const float4* ar = (const float4*)(AB + (size_t)pi * 128 + hu * 32);
    const float4* br = (const float4*)(AB + (size_t)pj * 128 + 64 + hu * 32);
#pragma unroll
    for (int m = 0; m < 8; ++m) {
      float4 a = ar[m], b = br[m];
      int u = hu * 32 + m * 4;
      zt[u][pp]     = fmaxf(a.x + b.x, 0.f);
      zt[u + 1][pp] = fmaxf(a.y + b.y, 0.f);
      zt[u + 2][pp] = fmaxf(a.z + b.z, 0.f);
      zt[u + 3][pp] = fmaxf(a.w + b.w, 0.f);
    }
  }
  __syncthreads();

  // ---- layer 2: out[p][hu*43+j] = bp2 + sum_t z[t]*Wp2[t][hu*43+j]
  {
    float acc2[43];
#pragma unroll
    for (int j = 0; j < 43; ++j) acc2[j] = bp2[hu * 43 + j];
#pragma unroll 2
    for (int t = 0; t < 64; ++t) {
      float zv = zt[t][pp];
#pragma unroll
      for (int j = 0; j < 43; ++j)
        acc2[j] += zv * Wp2[t * 86 + hu * 43 + j];  // uniform, j-consecutive
    }
#pragma unroll
    for (int j = 0; j < 43; ++j) out[(size_t)p * 86 + hu * 43 + j] = acc2[j];
  }
}

extern "C" void kernel_launch(void* const* d_in, const int* in_sizes, int n_in,
                              void* d_out, int out_size, void* d_ws, size_t ws_size,
                              hipStream_t stream) {
  (void)in_sizes; (void)n_in; (void)out_size; (void)ws_size;
  const float* x      = (const float*)d_in[0];
  const int*   ei     = (const int*)d_in[1];
  const int*   pairs  = (const int*)d_in[2];
  const float* W1     = (const float*)d_in[3];
  const float* a_src1 = (const float*)d_in[4];
  const float* a_dst1 = (const float*)d_in[5];
  const float* b1     = (const float*)d_in[6];
  const float* W2     = (const float*)d_in[7];
  const float* a_src2 = (const float*)d_in[8];
  const float* a_dst2 = (const float*)d_in[9];
  const float* b2     = (const float*)d_in[10];
  const float* Wp1    = (const float*)d_in[11];
  const float* bp1    = (const float*)d_in[12];
  const float* Wp2    = (const float*)d_in[13];
  const float* bp2    = (const float*)d_in[14];
  float* out = (float*)d_out;

  char* w = (char*)d_ws;
  auto alloc = [&](size_t bytes) -> void* {
    void* pp = (void*)w;
    w += (bytes + 255) & ~(size_t)255;
    return pp;
  };
  __half* h1h16 = (__half*)alloc((size_t)NN * 256 * 2);  // head-major [4][NN][64] fp16
  float*  AS1   = (float*)alloc((size_t)NN * 4 * 4);
  float*  AD1   = (float*)alloc((size_t)NN * 4 * 4);
  float*  h1agg = (float*)alloc((size_t)NN * 256 * 4);
  __half* h2h16 = (__half*)alloc((size_t)NN * 64 * 2);   // fp16 gather copy
  float*  AS2   = (float*)alloc((size_t)NN * 4);
  float*  AD2   = (float*)alloc((size_t)NN * 4);
  float*  h2agg = (float*)alloc((size_t)NN * 64 * 4);
  float*  AB    = (float*)alloc((size_t)NN * 128 * 4);
  int*    rp    = (int*)alloc((size_t)(NN + 1) * 4);
  int*    cnt   = (int*)alloc((size_t)NN * 4);
  int*    cur   = (int*)alloc((size_t)NN * 4);
  int*    col   = (int*)alloc((size_t)NEE * 4);

  hipMemsetAsync(cnt, 0, (size_t)NN * 4, stream);
  hipMemsetAsync(cur, 0, (size_t)NN * 4, stream);

  const int EB = (NEE + 255) / 256;  // 2579
  k_hist<<<EB, 256, 0, stream>>>(ei, cnt);
  k_scan<<<1, 1024, 0, stream>>>(cnt, rp);
  k_scatter<<<EB, 256, 0, stream>>>(ei, rp, cur, col);

  k_gemm1<<<NN / 16, 128, 0, stream>>>(x, W1, a_src1, a_dst1, h1h16, AS1, AD1);
  k_agg1<<<NN, 256, 0, stream>>>(rp, col, AS1, AD1, h1h16, b1, h1agg);

  k_gemm2<<<NN / 16, 256, 0, stream>>>(h1agg, W2, a_src2, a_dst2, h2h16, AS2, AD2);
  k_agg2<<<NN / 4, 256, 0, stream>>>(rp, col, AS2, AD2, h2h16, b2, h2agg);

  k_predot<<<NN / 16, 128, 0, stream>>>(h2agg, Wp1, bp1, AB);
  k_pairs<<<NP / 64, PB, 0, stream>>>(pairs, AB, Wp2, bp2, out);
}

// Round 16
// 330.766 us; speedup vs baseline: 1.5351x; 1.0768x over previous
//
#include <hip/hip_runtime.h>
#include <hip/hip_fp16.h>

#define NN 20000      // nodes
#define NE 640000     // edges (without self loops)
#define NEE 660000    // edges + self loops
#define NP 200000     // drug pairs
#define NEG 0.2f      // leaky relu slope

typedef _Float16 f16;
typedef __attribute__((ext_vector_type(4))) _Float16 f16x4;
typedef __attribute__((ext_vector_type(8))) _Float16 f16x8;
typedef __attribute__((ext_vector_type(4))) float f32x4;

// ---------------- CSR build ----------------
__global__ void k_hist(const int* __restrict__ ei, int* __restrict__ cnt) {
  int i = blockIdx.x * 256 + threadIdx.x;
  if (i >= NEE) return;
  int d = (i < NE) ? ei[NE + i] : (i - NE);
  atomicAdd(&cnt[d], 1);
}

__global__ __launch_bounds__(1024) void k_scan(const int* __restrict__ cnt, int* __restrict__ rp) {
  __shared__ int ps[1024];
  const int CH = 20;  // 1024*20 = 20480 >= 20000
  int t = threadIdx.x;
  int lo = t * CH, hi = lo + CH;
  if (hi > NN) hi = NN;
  if (lo > NN) lo = NN;
  int s = 0;
  for (int i = lo; i < hi; ++i) s += cnt[i];
  ps[t] = s;
  __syncthreads();
  for (int off = 1; off < 1024; off <<= 1) {
    int v = (t >= off) ? ps[t - off] : 0;
    __syncthreads();
    ps[t] += v;
    __syncthreads();
  }
  int run = (t > 0) ? ps[t - 1] : 0;
  for (int i = lo; i < hi; ++i) { rp[i] = run; run += cnt[i]; }
  if (t == 1023) rp[NN] = ps[1023];
}

__global__ void k_scatter(const int* __restrict__ ei, const int* __restrict__ rp,
                          int* __restrict__ cur, int* __restrict__ col) {
  int i = blockIdx.x * 256 + threadIdx.x;
  if (i >= NEE) return;
  int s, d;
  if (i < NE) { s = ei[i]; d = ei[NE + i]; } else { s = i - NE; d = s; }
  int pos = atomicAdd(&cur[d], 1);
  col[rp[d] + pos] = s;
}

// ---------------- convert: x -> fp16 (row-major), W1 -> fp16 TRANSPOSED [n][k] -----------
__global__ void k_cvt(const float* __restrict__ x, const float* __restrict__ W1,
                      f16* __restrict__ xh, f16* __restrict__ W1T) {
  int i = blockIdx.x * 256 + threadIdx.x;
  if (i < NN * 256 / 4) {
    float4 v = ((const float4*)x)[i];
    f16x4 h; h.x = (f16)v.x; h.y = (f16)v.y; h.z = (f16)v.z; h.w = (f16)v.w;
    *(f16x4*)(xh + (size_t)i * 4) = h;
  } else {
    int j = i - NN * 256 / 4;
    if (j < 256 * 256) {
      int r = j >> 8, c = j & 255;
      W1T[c * 256 + r] = (f16)W1[j];
    }
  }
}

// ---------------- GEMM1 v3 (MFMA): h1 = x @ W1 via mfma_f32_16x16x32_f16 ----------------
// Block = 16 rows x 256 cols, 4 waves; wave w computes head w (4 n-tiles of 16, 8 k-steps).
// A frag: lane l -> A[l&15][(l>>4)*8+i] (16B contiguous from LDS xs, row-pad 264 -> 2-way
// bank alias = free). B frag: lane l -> B[k][l&15] = W1T[(n0+(l&15))*256 + k..] (16B, L2-hot).
// C/D frag (m89): col = lane&15, row = (lane>>4)*4 + reg. Alphas reduced from frags via
// 16-lane shfl_xor. Output h1 fp16 head-major (gather-only tensor, round-14-proven).
__global__ __launch_bounds__(256) void k_gemm1(
    const f16* __restrict__ xh, const f16* __restrict__ W1T,
    const float* __restrict__ as1, const float* __restrict__ ad1,
    __half* __restrict__ h1h16, float* __restrict__ AS1, float* __restrict__ AD1) {
  __shared__ f16 xs[16][264];     // 16 rows x 256 k, row stride 528B
  int tid = threadIdx.x;
  int base = blockIdx.x * 16;
  {
    int r = tid >> 4, ch = tid & 15;   // each thread stages 16 f16 (32B) of one row
    const uint4* src = (const uint4*)(xh + (size_t)(base + r) * 256 + ch * 16);
    uint4 v0 = src[0], v1 = src[1];
    *(uint4*)&xs[r][ch * 16] = v0;
    *(uint4*)&xs[r][ch * 16 + 8] = v1;
  }
  __syncthreads();
  int wv = tid >> 6, lane = tid & 63;
  int head = wv;
  int lr = lane & 15, lk = lane >> 4;
  f32x4 acc[4] = {{0.f,0.f,0.f,0.f},{0.f,0.f,0.f,0.f},{0.f,0.f,0.f,0.f},{0.f,0.f,0.f,0.f}};
#pragma unroll
  for (int k0 = 0; k0 < 256; k0 += 32) {
    f16x8 a = *(const f16x8*)&xs[lr][k0 + lk * 8];
#pragma unroll
    for (int nt = 0; nt < 4; ++nt) {
      int n = head * 64 + nt * 16 + lr;
      f16x8 b = *(const f16x8*)(W1T + (size_t)n * 256 + k0 + lk * 8);
      acc[nt] = __builtin_amdgcn_mfma_f32_16x16x32_f16(a, b, acc[nt], 0, 0, 0);
    }
  }
  // write h1 fp16 head-major
#pragma unroll
  for (int nt = 0; nt < 4; ++nt) {
    int cc = nt * 16 + lr;
#pragma unroll
    for (int r = 0; r < 4; ++r) {
      int row = lk * 4 + r;
      h1h16[((size_t)head * NN + base + row) * 64 + cc] = __float2half(acc[nt][r]);
    }
  }
  // alphas: per row, dot over this head's 64 cols then 16-lane reduce
#pragma unroll
  for (int r = 0; r < 4; ++r) {
    float ps = 0.f, pd = 0.f;
#pragma unroll
    for (int nt = 0; nt < 4; ++nt) {
      int cc = nt * 16 + lr;
      ps += acc[nt][r] * as1[head * 64 + cc];
      pd += acc[nt][r] * ad1[head * 64 + cc];
    }
#pragma unroll
    for (int off = 1; off < 16; off <<= 1) {
      ps += __shfl_xor(ps, off);
      pd += __shfl_xor(pd, off);
    }
    if (lr == 0) {
      int n = base + lk * 4 + r;
      AS1[n * 4 + head] = ps;
      AD1[n * 4 + head] = pd;
    }
  }
}

// ---------------- GAT layer-1 aggregation: XCD-pinned heads, fp16 gather, pipelined ------
__global__ __launch_bounds__(256, 4) void k_agg1(
    const int* __restrict__ rp, const int* __restrict__ col,
    const float* __restrict__ AS1, const float* __restrict__ AD1,
    const __half* __restrict__ h1h16, const float* __restrict__ b1,
    float* __restrict__ out) {
  int b = blockIdx.x;
  int xcd = b & 7;
  int head = xcd >> 1;
  int grp = (b >> 3) * 2 + (xcd & 1);      // 0..4999, bijective per head
  int wave = threadIdx.x >> 6, lane = threadIdx.x & 63;
  int n = grp * 4 + wave;
  int g = lane >> 4, c4 = (lane & 15) * 4;
  int e0 = rp[n], e1 = rp[n + 1];
  const __half* hs = h1h16 + (size_t)head * NN * 64;
  float adv = AD1[n * 4 + head];
  float ax = 0.f, ay = 0.f, az = 0.f, aw = 0.f, den = 0.f;

  int ee = e0 + g;
  bool v = ee < e1;
  int ec = v ? ee : e1 - 1;
  int s = col[ec];
  float asv = AS1[s * 4 + head];

  for (int e = e0; e < e1; e += 4) {
    int een = e + 4 + g;
    bool vn = een < e1;
    int ecn = vn ? een : e1 - 1;
    int sn = col[ecn];
    float asn = AS1[sn * 4 + head];
    float ev = asv + adv;
    ev = ev > 0.f ? ev : NEG * ev;
    float p = v ? __expf(ev) : 0.f;
    __half2 h01 = *(const __half2*)(hs + (size_t)s * 64 + c4);
    __half2 h23 = *(const __half2*)(hs + (size_t)s * 64 + c4 + 2);
    float2 f0 = __half22float2(h01), f1 = __half22float2(h23);
    ax += p * f0.x; ay += p * f0.y; az += p * f1.x; aw += p * f1.y;
    den += p;
    s = sn; asv = asn; v = vn;
  }
  ax += __shfl_xor(ax, 16); ax += __shfl_xor(ax, 32);
  ay += __shfl_xor(ay, 16); ay += __shfl_xor(ay, 32);
  az += __shfl_xor(az, 16); az += __shfl_xor(az, 32);
  aw += __shfl_xor(aw, 16); aw += __shfl_xor(aw, 32);
  den += __shfl_xor(den, 16); den += __shfl_xor(den, 32);
  if (lane < 16) {
    float inv = 1.f / den;
    int cbase = head * 64 + c4;
    float4 bv = *(const float4*)(b1 + cbase);
    float4 o;
    o.x = ax * inv + bv.x; o.y = ay * inv + bv.y;
    o.z = az * inv + bv.z; o.w = aw * inv + bv.w;
    o.x = o.x > 0.f ? o.x : __expf(o.x) - 1.f;
    o.y = o.y > 0.f ? o.y : __expf(o.y) - 1.f;
    o.z = o.z > 0.f ? o.z : __expf(o.z) - 1.f;
    o.w = o.w > 0.f ? o.w : __expf(o.w) - 1.f;
    *(float4*)(out + (size_t)n * 256 + cbase) = o;
  }
}

// ---------------- GEMM2: h2 = h1act @ W2, fp16 store (gather-only tensor) + alphas -------
__global__ __launch_bounds__(256) void k_gemm2(
    const float* __restrict__ h1a, const float* __restrict__ W2,
    const float* __restrict__ as2, const float* __restrict__ ad2,
    __half* __restrict__ h2h16, float* __restrict__ AS2, float* __restrict__ AD2) {
  __shared__ float xsT[256][20];
  int tid = threadIdx.x;
  int c = tid & 63, w = tid >> 6;  // wave w handles rows 4w..4w+3
  int base = blockIdx.x * 16;
  for (int i = tid; i < 16 * 256; i += 256) {
    int r = i >> 8, k = i & 255;
    xsT[k][r] = h1a[(base + r) * 256 + k];
  }
  __syncthreads();
  float acc[4] = {0.f, 0.f, 0.f, 0.f};
#pragma unroll 2
  for (int k = 0; k < 256; ++k) {
    float wv = W2[k * 64 + c];
    float4 xv = *(const float4*)&xsT[k][w * 4];
    acc[0] += xv.x * wv; acc[1] += xv.y * wv; acc[2] += xv.z * wv; acc[3] += xv.w * wv;
  }
  float asv = as2[c], adv = ad2[c];
#pragma unroll
  for (int rr = 0; rr < 4; ++rr) {
    int row = base + w * 4 + rr;
    h2h16[(size_t)row * 64 + c] = __float2half(acc[rr]);
    float vs = acc[rr] * asv, vd = acc[rr] * adv;
#pragma unroll
    for (int off = 32; off > 0; off >>= 1) {
      vs += __shfl_xor(vs, off);
      vd += __shfl_xor(vd, off);
    }
    if (c == 0) { AS2[row] = vs; AD2[row] = vd; }
  }
}

// ---------------- GAT layer-2 aggregation: fp16 gather + pipelined loads ----------------
__global__ __launch_bounds__(256, 4) void k_agg2(
    const int* __restrict__ rp, const int* __restrict__ col,
    const float* __restrict__ AS2, const float* __restrict__ AD2,
    const __half* __restrict__ h2h16, const float* __restrict__ b2,
    float* __restrict__ out) {
  int wave = threadIdx.x >> 6, lane = threadIdx.x & 63;
  int n = blockIdx.x * 4 + wave;
  int g = lane >> 4, c4 = (lane & 15) * 4;
  int e0 = rp[n], e1 = rp[n + 1];
  float adv = AD2[n];
  float ax = 0.f, ay = 0.f, az = 0.f, aw = 0.f, den = 0.f;

  int ee = e0 + g;
  bool v = ee < e1;
  int ec = v ? ee : e1 - 1;
  int s = col[ec];
  float asv = AS2[s];

  for (int e = e0; e < e1; e += 4) {
    int een = e + 4 + g;
    bool vn = een < e1;
    int ecn = vn ? een : e1 - 1;
    int sn = col[ecn];
    float asn = AS2[sn];
    float ev = asv + adv;
    ev = ev > 0.f ? ev : NEG * ev;
    float p = v ? __expf(ev) : 0.f;
    __half2 h01 = *(const __half2*)(h2h16 + (size_t)s * 64 + c4);
    __half2 h23 = *(const __half2*)(h2h16 + (size_t)s * 64 + c4 + 2);
    float2 f0 = __half22float2(h01), f1 = __half22float2(h23);
    ax += p * f0.x; ay += p * f0.y; az += p * f1.x; aw += p * f1.y;
    den += p;
    s = sn; asv = asn; v = vn;
  }
  ax += __shfl_xor(ax, 16); ax += __shfl_xor(ax, 32);
  ay += __shfl_xor(ay, 16); ay += __shfl_xor(ay, 32);
  az += __shfl_xor(az, 16); az += __shfl_xor(az, 32);
  aw += __shfl_xor(aw, 16); aw += __shfl_xor(aw, 32);
  den += __shfl_xor(den, 16); den += __shfl_xor(den, 32);
  if (lane < 16) {
    float inv = 1.f / den;
    float4 bv = *(const float4*)(b2 + c4);
    float4 o;
    o.x = ax * inv + bv.x; o.y = ay * inv + bv.y;
    o.z = az * inv + bv.z; o.w = aw * inv + bv.w;
    o.x = o.x > 0.f ? o.x : __expf(o.x) - 1.f;
    o.y = o.y > 0.f ? o.y : __expf(o.y) - 1.f;
    o.z = o.z > 0.f ? o.z : __expf(o.z) - 1.f;
    o.w = o.w > 0.f ? o.w : __expf(o.w) - 1.f;
    *(float4*)(out + (size_t)n * 64 + c4) = o;
  }
}

// ---------------- per-node pair-MLP layer-1 precompute ----------------
__global__ __launch_bounds__(128) void k_predot(
    const float* __restrict__ h2a, const float* __restrict__ Wp1,
    const float* __restrict__ bp1, float* __restrict__ AB) {
  __shared__ float xsT[64][20];   // [k][row], 16 rows, pad 20
  int c = threadIdx.x;            // 0..127
  int base = blockIdx.x * 16;
  for (int i = threadIdx.x; i < 16 * 64; i += 128) {
    int r = i >> 6, k = i & 63;
    xsT[k][r] = h2a[(size_t)(base + r) * 64 + k];
  }
  __syncthreads();
  int part = c >> 6, u = c & 63;
  float bv = (part == 0) ? bp1[u] : 0.f;
  float acc[16];
#pragma unroll
  for (int r = 0; r < 16; ++r) acc[r] = bv;
#pragma unroll 2
  for (int k = 0; k < 64; ++k) {
    float wv = Wp1[(size_t)(part * 64 + k) * 64 + u];  // coalesced per half-wave
    const float4* xr = (const float4*)&xsT[k][0];
    float4 x0 = xr[0], x1 = xr[1], x2 = xr[2], x3 = xr[3];
    acc[0] += x0.x * wv; acc[1] += x0.y * wv; acc[2] += x0.z * wv; acc[3] += x0.w * wv;
    acc[4] += x1.x * wv; acc[5] += x1.y * wv; acc[6] += x1.z * wv; acc[7] += x1.w * wv;
    acc[8] += x2.x * wv; acc[9] += x2.y * wv; acc[10] += x2.z * wv; acc[11] += x2.w * wv;
    acc[12] += x3.x * wv; acc[13] += x3.y * wv; acc[14] += x3.z * wv; acc[15] += x3.w * wv;
  }
#pragma unroll
  for (int r = 0; r < 16; ++r) AB[(size_t)(base + r) * 128 + c] = acc[r];
}

// ---------------- pair MLP v12: z = relu(A[pi]+B[pj]) gather + v6 layer 2 ----------------
#define PB 128

__global__ __launch_bounds__(PB, 4) void k_pairs(
    const int* __restrict__ pairs, const float* __restrict__ AB,
    const float* __restrict__ Wp2, const float* __restrict__ bp2,
    float* __restrict__ out) {
  __shared__ float zt[64][66];  // [t][pair]
  int tid = threadIdx.x;
  int pp = tid & 63;                                      // pair within block
  int hu = __builtin_amdgcn_readfirstlane(tid >> 6);      // wave id 0/1, provably uniform
  int p = blockIdx.x * 64 + pp;
  int pi = pairs[2 * p], pj = pairs[2 * p + 1];

  // ---- z half hu: z[hu*32+u] = relu(A[pi][hu*32+u] + B[pj][hu*32+u])   (bp1 folded in A)
  {
    const float4* ar = (const float4*)(AB + (size_t)pi * 128 + hu * 32);
    const float4* br = (const float4*)(AB + (size_t)pj * 128 + 64 + hu * 32);
#pragma unroll
    for (int m = 0; m < 8; ++m) {
      float4 a = ar[m], b = br[m];
      int u = hu * 32 + m * 4;
      zt[u][pp]     = fmaxf(a.x + b.x, 0.f);
      zt[u + 1][pp] = fmaxf(a.y + b.y, 0.f);
      zt[u + 2][pp] = fmaxf(a.z + b.z, 0.f);
      zt[u + 3][pp] = fmaxf(a.w + b.w, 0.f);
    }
  }
  __syncthreads();

  // ---- layer 2: out[p][hu*43+j] = bp2 + sum_t z[t]*Wp2[t][hu*43+j]
  {
    float acc2[43];
#pragma unroll
    for (int j = 0; j < 43; ++j) acc2[j] = bp2[hu * 43 + j];
#pragma unroll 2
    for (int t = 0; t < 64; ++t) {
      float zv = zt[t][pp];
#pragma unroll
      for (int j = 0; j < 43; ++j)
        acc2[j] += zv * Wp2[t * 86 + hu * 43 + j];  // uniform, j-consecutive
    }
#pragma unroll
    for (int j = 0; j < 43; ++j) out[(size_t)p * 86 + hu * 43 + j] = acc2[j];
  }
}

extern "C" void kernel_launch(void* const* d_in, const int* in_sizes, int n_in,
                              void* d_out, int out_size, void* d_ws, size_t ws_size,
                              hipStream_t stream) {
  (void)in_sizes; (void)n_in; (void)out_size; (void)ws_size;
  const float* x      = (const float*)d_in[0];
  const int*   ei     = (const int*)d_in[1];
  const int*   pairs  = (const int*)d_in[2];
  const float* W1     = (const float*)d_in[3];
  const float* a_src1 = (const float*)d_in[4];
  const float* a_dst1 = (const float*)d_in[5];
  const float* b1     = (const float*)d_in[6];
  const float* W2     = (const float*)d_in[7];
  const float* a_src2 = (const float*)d_in[8];
  const float* a_dst2 = (const float*)d_in[9];
  const float* b2     = (const float*)d_in[10];
  const float* Wp1    = (const float*)d_in[11];
  const float* bp1    = (const float*)d_in[12];
  const float* Wp2    = (const float*)d_in[13];
  const float* bp2    = (const float*)d_in[14];
  float* out = (float*)d_out;

  char* w = (char*)d_ws;
  auto alloc = [&](size_t bytes) -> void* {
    void* pp = (void*)w;
    w += (bytes + 255) & ~(size_t)255;
    return pp;
  };
  __half* h1h16 = (__half*)alloc((size_t)NN * 256 * 2);  // head-major [4][NN][64] fp16
  float*  AS1   = (float*)alloc((size_t)NN * 4 * 4);
  float*  AD1   = (float*)alloc((size_t)NN * 4 * 4);
  float*  h1agg = (float*)alloc((size_t)NN * 256 * 4);
  __half* h2h16 = (__half*)alloc((size_t)NN * 64 * 2);   // fp16 gather copy
  float*  AS2   = (float*)alloc((size_t)NN * 4);
  float*  AD2   = (float*)alloc((size_t)NN * 4);
  float*  h2agg = (float*)alloc((size_t)NN * 64 * 4);
  float*  AB    = (float*)alloc((size_t)NN * 128 * 4);
  f16*    xh    = (f16*)alloc((size_t)NN * 256 * 2);     // fp16 copy of x
  f16*    W1T   = (f16*)alloc((size_t)256 * 256 * 2);    // fp16 W1 transposed [n][k]
  int*    rp    = (int*)alloc((size_t)(NN + 1) * 4);
  int*    cnt   = (int*)alloc((size_t)NN * 4);
  int*    cur   = (int*)alloc((size_t)NN * 4);
  int*    col   = (int*)alloc((size_t)NEE * 4);

  hipMemsetAsync(cnt, 0, (size_t)NN * 4, stream);
  hipMemsetAsync(cur, 0, (size_t)NN * 4, stream);

  const int EB = (NEE + 255) / 256;  // 2579
  k_hist<<<EB, 256, 0, stream>>>(ei, cnt);
  k_scan<<<1, 1024, 0, stream>>>(cnt, rp);
  k_scatter<<<EB, 256, 0, stream>>>(ei, rp, cur, col);
  k_cvt<<<NN * 256 / 4 / 256 + 256, 256, 0, stream>>>(x, W1, xh, W1T);  // 5256 blocks

  k_gemm1<<<NN / 16, 256, 0, stream>>>(xh, W1T, a_src1, a_dst1, h1h16, AS1, AD1);
  k_agg1<<<NN, 256, 0, stream>>>(rp, col, AS1, AD1, h1h16, b1, h1agg);

  k_gemm2<<<NN / 16, 256, 0, stream>>>(h1agg, W2, a_src2, a_dst2, h2h16, AS2, AD2);
  k_agg2<<<NN / 4, 256, 0, stream>>>(rp, col, AS2, AD2, h2h16, b2, h2agg);

  k_predot<<<NN / 16, 128, 0, stream>>>(h2agg, Wp1, bp1, AB);
  k_pairs<<<NP / 64, PB, 0, stream>>>(pairs, AB, Wp2, bp2, out);
}

// Round 17
// 306.975 us; speedup vs baseline: 1.6541x; 1.0775x over previous
//
#include <hip/hip_runtime.h>
#include <hip/hip_fp16.h>

#define NN 20000      // nodes
#define NE 640000     // edges (without self loops)
#define NEE 660000    // edges + self loops
#define NP 200000     // drug pairs
#define NEG 0.2f      // leaky relu slope

typedef _Float16 f16;
typedef __attribute__((ext_vector_type(4))) _Float16 f16x4;
typedef __attribute__((ext_vector_type(8))) _Float16 f16x8;
typedef __attribute__((ext_vector_type(4))) float f32x4;

// ---------------- CSR build ----------------
__global__ void k_hist(const int* __restrict__ ei, int* __restrict__ cnt) {
  int i = blockIdx.x * 256 + threadIdx.x;
  if (i >= NEE) return;
  int d = (i < NE) ? ei[NE + i] : (i - NE);
  atomicAdd(&cnt[d], 1);
}

__global__ __launch_bounds__(1024) void k_scan(const int* __restrict__ cnt, int* __restrict__ rp) {
  __shared__ int ps[1024];
  const int CH = 20;  // 1024*20 = 20480 >= 20000
  int t = threadIdx.x;
  int lo = t * CH, hi = lo + CH;
  if (hi > NN) hi = NN;
  if (lo > NN) lo = NN;
  int s = 0;
  for (int i = lo; i < hi; ++i) s += cnt[i];
  ps[t] = s;
  __syncthreads();
  for (int off = 1; off < 1024; off <<= 1) {
    int v = (t >= off) ? ps[t - off] : 0;
    __syncthreads();
    ps[t] += v;
    __syncthreads();
  }
  int run = (t > 0) ? ps[t - 1] : 0;
  for (int i = lo; i < hi; ++i) { rp[i] = run; run += cnt[i]; }
  if (t == 1023) rp[NN] = ps[1023];
}

__global__ void k_scatter(const int* __restrict__ ei, const int* __restrict__ rp,
                          int* __restrict__ cur, int* __restrict__ col) {
  int i = blockIdx.x * 256 + threadIdx.x;
  if (i >= NEE) return;
  int s, d;
  if (i < NE) { s = ei[i]; d = ei[NE + i]; } else { s = i - NE; d = s; }
  int pos = atomicAdd(&cur[d], 1);
  col[rp[d] + pos] = s;
}

// ---------------- convert: x -> fp16 (row-major), W1 -> fp16 TRANSPOSED [n][k] -----------
__global__ void k_cvt(const float* __restrict__ x, const float* __restrict__ W1,
                      f16* __restrict__ xh, f16* __restrict__ W1T) {
  int i = blockIdx.x * 256 + threadIdx.x;
  if (i < NN * 256 / 4) {
    float4 v = ((const float4*)x)[i];
    f16x4 h; h.x = (f16)v.x; h.y = (f16)v.y; h.z = (f16)v.z; h.w = (f16)v.w;
    *(f16x4*)(xh + (size_t)i * 4) = h;
  } else {
    int j = i - NN * 256 / 4;
    if (j < 256 * 256) {
      int r = j >> 8, c = j & 255;
      W1T[c * 256 + r] = (f16)W1[j];
    }
  }
}

// ---------------- GEMM1 v3 (MFMA): h1 = x @ W1 via mfma_f32_16x16x32_f16 ----------------
__global__ __launch_bounds__(256) void k_gemm1(
    const f16* __restrict__ xh, const f16* __restrict__ W1T,
    const float* __restrict__ as1, const float* __restrict__ ad1,
    __half* __restrict__ h1h16, float* __restrict__ AS1, float* __restrict__ AD1) {
  __shared__ f16 xs[16][264];     // 16 rows x 256 k, row stride 528B
  int tid = threadIdx.x;
  int base = blockIdx.x * 16;
  {
    int r = tid >> 4, ch = tid & 15;   // each thread stages 16 f16 (32B) of one row
    const uint4* src = (const uint4*)(xh + (size_t)(base + r) * 256 + ch * 16);
    uint4 v0 = src[0], v1 = src[1];
    *(uint4*)&xs[r][ch * 16] = v0;
    *(uint4*)&xs[r][ch * 16 + 8] = v1;
  }
  __syncthreads();
  int wv = tid >> 6, lane = tid & 63;
  int head = wv;
  int lr = lane & 15, lk = lane >> 4;
  f32x4 acc[4] = {{0.f,0.f,0.f,0.f},{0.f,0.f,0.f,0.f},{0.f,0.f,0.f,0.f},{0.f,0.f,0.f,0.f}};
#pragma unroll
  for (int k0 = 0; k0 < 256; k0 += 32) {
    f16x8 a = *(const f16x8*)&xs[lr][k0 + lk * 8];
#pragma unroll
    for (int nt = 0; nt < 4; ++nt) {
      int n = head * 64 + nt * 16 + lr;
      f16x8 b = *(const f16x8*)(W1T + (size_t)n * 256 + k0 + lk * 8);
      acc[nt] = __builtin_amdgcn_mfma_f32_16x16x32_f16(a, b, acc[nt], 0, 0, 0);
    }
  }
#pragma unroll
  for (int nt = 0; nt < 4; ++nt) {
    int cc = nt * 16 + lr;
#pragma unroll
    for (int r = 0; r < 4; ++r) {
      int row = lk * 4 + r;
      h1h16[((size_t)head * NN + base + row) * 64 + cc] = __float2half(acc[nt][r]);
    }
  }
#pragma unroll
  for (int r = 0; r < 4; ++r) {
    float ps = 0.f, pd = 0.f;
#pragma unroll
    for (int nt = 0; nt < 4; ++nt) {
      int cc = nt * 16 + lr;
      ps += acc[nt][r] * as1[head * 64 + cc];
      pd += acc[nt][r] * ad1[head * 64 + cc];
    }
#pragma unroll
    for (int off = 1; off < 16; off <<= 1) {
      ps += __shfl_xor(ps, off);
      pd += __shfl_xor(pd, off);
    }
    if (lr == 0) {
      int n = base + lk * 4 + r;
      AS1[n * 4 + head] = ps;
      AD1[n * 4 + head] = pd;
    }
  }
}

// ---------------- GAT layer-1 aggregation v4: 8 edges x 8 lanes, XCD-pinned, pipelined ---
// Round-16 diagnosis: issue-bound (FETCH = unique bytes, VALU 58%, 290 GB/s). Widening
// 4x16 -> 8x8 halves the per-edge overhead (col/AS1/exp/loop amortize over 8 edges per
// wave-iteration; one v_exp covers 8 distinct edges). Lane gathers 16B (8 fp16 cols) ->
// still 1KB per wave gather instruction, 128B contiguous per edge.
__global__ __launch_bounds__(256, 4) void k_agg1(
    const int* __restrict__ rp, const int* __restrict__ col,
    const float* __restrict__ AS1, const float* __restrict__ AD1,
    const __half* __restrict__ h1h16, const float* __restrict__ b1,
    float* __restrict__ out) {
  int b = blockIdx.x;
  int xcd = b & 7;
  int head = xcd >> 1;
  int grp = (b >> 3) * 2 + (xcd & 1);      // 0..4999, bijective per head
  int wave = threadIdx.x >> 6, lane = threadIdx.x & 63;
  int n = grp * 4 + wave;
  int g = lane >> 3, c8 = (lane & 7) * 8;  // edge group 0..7, col base (8 fp16 = 16B)
  int e0 = rp[n], e1 = rp[n + 1];
  const __half* hs = h1h16 + (size_t)head * NN * 64;
  float adv = AD1[n * 4 + head];
  float acc[8] = {0.f,0.f,0.f,0.f,0.f,0.f,0.f,0.f};
  float den = 0.f;

  // prologue
  int ee = e0 + g;
  bool v = ee < e1;
  int ec = v ? ee : e1 - 1;
  int s = col[ec];
  float asv = AS1[s * 4 + head];

  for (int e = e0; e < e1; e += 8) {
    // prefetch next iteration (clamped, always in-bounds)
    int een = e + 8 + g;
    bool vn = een < e1;
    int ecn = vn ? een : e1 - 1;
    int sn = col[ecn];
    float asn = AS1[sn * 4 + head];
    // compute current
    float ev = asv + adv;
    ev = fmaxf(ev, NEG * ev);              // leaky relu
    float p = v ? __expf(ev) : 0.f;
    float4 raw = *(const float4*)(hs + (size_t)s * 64 + c8);   // 16B = 8 fp16
    const __half2* hp = (const __half2*)&raw;
#pragma unroll
    for (int m = 0; m < 4; ++m) {
      float2 f = __half22float2(hp[m]);
      acc[m * 2]     += p * f.x;
      acc[m * 2 + 1] += p * f.y;
    }
    den += p;
    s = sn; asv = asn; v = vn;
  }
#pragma unroll
  for (int i = 0; i < 8; ++i) {
    acc[i] += __shfl_xor(acc[i], 8);
    acc[i] += __shfl_xor(acc[i], 16);
    acc[i] += __shfl_xor(acc[i], 32);
  }
  den += __shfl_xor(den, 8); den += __shfl_xor(den, 16); den += __shfl_xor(den, 32);
  if (lane < 8) {
    float inv = 1.f / den;
    int cbase = head * 64 + lane * 8;
    float o[8];
#pragma unroll
    for (int i = 0; i < 8; ++i) {
      float r = acc[i] * inv + b1[cbase + i];
      o[i] = r > 0.f ? r : __expf(r) - 1.f;
    }
    *(float4*)(out + (size_t)n * 256 + cbase) = *(float4*)&o[0];
    *(float4*)(out + (size_t)n * 256 + cbase + 4) = *(float4*)&o[4];
  }
}

// ---------------- GEMM2: h2 = h1act @ W2, fp16 store (gather-only tensor) + alphas -------
__global__ __launch_bounds__(256) void k_gemm2(
    const float* __restrict__ h1a, const float* __restrict__ W2,
    const float* __restrict__ as2, const float* __restrict__ ad2,
    __half* __restrict__ h2h16, float* __restrict__ AS2, float* __restrict__ AD2) {
  __shared__ float xsT[256][20];
  int tid = threadIdx.x;
  int c = tid & 63, w = tid >> 6;  // wave w handles rows 4w..4w+3
  int base = blockIdx.x * 16;
  for (int i = tid; i < 16 * 256; i += 256) {
    int r = i >> 8, k = i & 255;
    xsT[k][r] = h1a[(base + r) * 256 + k];
  }
  __syncthreads();
  float acc[4] = {0.f, 0.f, 0.f, 0.f};
#pragma unroll 2
  for (int k = 0; k < 256; ++k) {
    float wv = W2[k * 64 + c];
    float4 xv = *(const float4*)&xsT[k][w * 4];
    acc[0] += xv.x * wv; acc[1] += xv.y * wv; acc[2] += xv.z * wv; acc[3] += xv.w * wv;
  }
  float asv = as2[c], adv = ad2[c];
#pragma unroll
  for (int rr = 0; rr < 4; ++rr) {
    int row = base + w * 4 + rr;
    h2h16[(size_t)row * 64 + c] = __float2half(acc[rr]);
    float vs = acc[rr] * asv, vd = acc[rr] * adv;
#pragma unroll
    for (int off = 32; off > 0; off >>= 1) {
      vs += __shfl_xor(vs, off);
      vd += __shfl_xor(vd, off);
    }
    if (c == 0) { AS2[row] = vs; AD2[row] = vd; }
  }
}

// ---------------- GAT layer-2 aggregation v4: 8 edges x 8 lanes, pipelined ---------------
__global__ __launch_bounds__(256, 4) void k_agg2(
    const int* __restrict__ rp, const int* __restrict__ col,
    const float* __restrict__ AS2, const float* __restrict__ AD2,
    const __half* __restrict__ h2h16, const float* __restrict__ b2,
    float* __restrict__ out) {
  int wave = threadIdx.x >> 6, lane = threadIdx.x & 63;
  int n = blockIdx.x * 4 + wave;
  int g = lane >> 3, c8 = (lane & 7) * 8;
  int e0 = rp[n], e1 = rp[n + 1];
  float adv = AD2[n];
  float acc[8] = {0.f,0.f,0.f,0.f,0.f,0.f,0.f,0.f};
  float den = 0.f;

  int ee = e0 + g;
  bool v = ee < e1;
  int ec = v ? ee : e1 - 1;
  int s = col[ec];
  float asv = AS2[s];

  for (int e = e0; e < e1; e += 8) {
    int een = e + 8 + g;
    bool vn = een < e1;
    int ecn = vn ? een : e1 - 1;
    int sn = col[ecn];
    float asn = AS2[sn];
    float ev = asv + adv;
    ev = fmaxf(ev, NEG * ev);
    float p = v ? __expf(ev) : 0.f;
    float4 raw = *(const float4*)(h2h16 + (size_t)s * 64 + c8);
    const __half2* hp = (const __half2*)&raw;
#pragma unroll
    for (int m = 0; m < 4; ++m) {
      float2 f = __half22float2(hp[m]);
      acc[m * 2]     += p * f.x;
      acc[m * 2 + 1] += p * f.y;
    }
    den += p;
    s = sn; asv = asn; v = vn;
  }
#pragma unroll
  for (int i = 0; i < 8; ++i) {
    acc[i] += __shfl_xor(acc[i], 8);
    acc[i] += __shfl_xor(acc[i], 16);
    acc[i] += __shfl_xor(acc[i], 32);
  }
  den += __shfl_xor(den, 8); den += __shfl_xor(den, 16); den += __shfl_xor(den, 32);
  if (lane < 8) {
    float inv = 1.f / den;
    int cbase = lane * 8;
    float o[8];
#pragma unroll
    for (int i = 0; i < 8; ++i) {
      float r = acc[i] * inv + b2[cbase + i];
      o[i] = r > 0.f ? r : __expf(r) - 1.f;
    }
    *(float4*)(out + (size_t)n * 64 + cbase) = *(float4*)&o[0];
    *(float4*)(out + (size_t)n * 64 + cbase + 4) = *(float4*)&o[4];
  }
}

// ---------------- per-node pair-MLP layer-1 precompute ----------------
__global__ __launch_bounds__(128) void k_predot(
    const float* __restrict__ h2a, const float* __restrict__ Wp1,
    const float* __restrict__ bp1, float* __restrict__ AB) {
  __shared__ float xsT[64][20];   // [k][row], 16 rows, pad 20
  int c = threadIdx.x;            // 0..127
  int base = blockIdx.x * 16;
  for (int i = threadIdx.x; i < 16 * 64; i += 128) {
    int r = i >> 6, k = i & 63;
    xsT[k][r] = h2a[(size_t)(base + r) * 64 + k];
  }
  __syncthreads();
  int part = c >> 6, u = c & 63;
  float bv = (part == 0) ? bp1[u] : 0.f;
  float acc[16];
#pragma unroll
  for (int r = 0; r < 16; ++r) acc[r] = bv;
#pragma unroll 2
  for (int k = 0; k < 64; ++k) {
    float wv = Wp1[(size_t)(part * 64 + k) * 64 + u];  // coalesced per half-wave
    const float4* xr = (const float4*)&xsT[k][0];
    float4 x0 = xr[0], x1 = xr[1], x2 = xr[2], x3 = xr[3];
    acc[0] += x0.x * wv; acc[1] += x0.y * wv; acc[2] += x0.z * wv; acc[3] += x0.w * wv;
    acc[4] += x1.x * wv; acc[5] += x1.y * wv; acc[6] += x1.z * wv; acc[7] += x1.w * wv;
    acc[8] += x2.x * wv; acc[9] += x2.y * wv; acc[10] += x2.z * wv; acc[11] += x2.w * wv;
    acc[12] += x3.x * wv; acc[13] += x3.y * wv; acc[14] += x3.z * wv; acc[15] += x3.w * wv;
  }
#pragma unroll
  for (int r = 0; r < 16; ++r) AB[(size_t)(base + r) * 128 + c] = acc[r];
}

// ---------------- pair MLP v12: z = relu(A[pi]+B[pj]) gather + v6 layer 2 ----------------
#define PB 128

__global__ __launch_bounds__(PB, 4) void k_pairs(
    const int* __restrict__ pairs, const float* __restrict__ AB,
    const float* __restrict__ Wp2, const float* __restrict__ bp2,
    float* __restrict__ out) {
  __shared__ float zt[64][66];  // [t][pair]
  int tid = threadIdx.x;
  int pp = tid & 63;                                      // pair within block
  int hu = __builtin_amdgcn_readfirstlane(tid >> 6);      // wave id 0/1, provably uniform
  int p = blockIdx.x * 64 + pp;
  int pi = pairs[2 * p], pj = pairs[2 * p + 1];

  // ---- z half hu: z[hu*32+u] = relu(A[pi][hu*32+u] + B[pj][hu*32+u])   (bp1 folded in A)
  {
    const float4* ar = (const float4*)(AB + (size_t)pi * 128 + hu * 32);
    const float4* br = (const float4*)(AB + (size_t)pj * 128 + 64 + hu * 32);
#pragma unroll
    for (int m = 0; m < 8; ++m) {
      float4 a = ar[m], b = br[m];
      int u = hu * 32 + m * 4;
      zt[u][pp]     = fmaxf(a.x + b.x, 0.f);
      zt[u + 1][pp] = fmaxf(a.y + b.y, 0.f);
      zt[u + 2][pp] = fmaxf(a.z + b.z, 0.f);
      zt[u + 3][pp] = fmaxf(a.w + b.w, 0.f);
    }
  }
  __syncthreads();

  // ---- layer 2: out[p][hu*43+j] = bp2 + sum_t z[t]*Wp2[t][hu*43+j]
  {
    float acc2[43];
#pragma unroll
    for (int j = 0; j < 43; ++j) acc2[j] = bp2[hu * 43 + j];
#pragma unroll 2
    for (int t = 0; t < 64; ++t) {
      float zv = zt[t][pp];
#pragma unroll
      for (int j = 0; j < 43; ++j)
        acc2[j] += zv * Wp2[t * 86 + hu * 43 + j];  // uniform, j-consecutive
    }
#pragma unroll
    for (int j = 0; j < 43; ++j) out[(size_t)p * 86 + hu * 43 + j] = acc2[j];
  }
}

extern "C" void kernel_launch(void* const* d_in, const int* in_sizes, int n_in,
                              void* d_out, int out_size, void* d_ws, size_t ws_size,
                              hipStream_t stream) {
  (void)in_sizes; (void)n_in; (void)out_size; (void)ws_size;
  const float* x      = (const float*)d_in[0];
  const int*   ei     = (const int*)d_in[1];
  const int*   pairs  = (const int*)d_in[2];
  const float* W1     = (const float*)d_in[3];
  const float* a_src1 = (const float*)d_in[4];
  const float* a_dst1 = (const float*)d_in[5];
  const float* b1     = (const float*)d_in[6];
  const float* W2     = (const float*)d_in[7];
  const float* a_src2 = (const float*)d_in[8];
  const float* a_dst2 = (const float*)d_in[9];
  const float* b2     = (const float*)d_in[10];
  const float* Wp1    = (const float*)d_in[11];
  const float* bp1    = (const float*)d_in[12];
  const float* Wp2    = (const float*)d_in[13];
  const float* bp2    = (const float*)d_in[14];
  float* out = (float*)d_out;

  char* w = (char*)d_ws;
  auto alloc = [&](size_t bytes) -> void* {
    void* pp = (void*)w;
    w += (bytes + 255) & ~(size_t)255;
    return pp;
  };
  __half* h1h16 = (__half*)alloc((size_t)NN * 256 * 2);  // head-major [4][NN][64] fp16
  float*  AS1   = (float*)alloc((size_t)NN * 4 * 4);
  float*  AD1   = (float*)alloc((size_t)NN * 4 * 4);
  float*  h1agg = (float*)alloc((size_t)NN * 256 * 4);
  __half* h2h16 = (__half*)alloc((size_t)NN * 64 * 2);   // fp16 gather copy
  float*  AS2   = (float*)alloc((size_t)NN * 4);
  float*  AD2   = (float*)alloc((size_t)NN * 4);
  float*  h2agg = (float*)alloc((size_t)NN * 64 * 4);
  float*  AB    = (float*)alloc((size_t)NN * 128 * 4);
  f16*    xh    = (f16*)alloc((size_t)NN * 256 * 2);     // fp16 copy of x
  f16*    W1T   = (f16*)alloc((size_t)256 * 256 * 2);    // fp16 W1 transposed [n][k]
  int*    rp    = (int*)alloc((size_t)(NN + 1) * 4);
  int*    cnt   = (int*)alloc((size_t)NN * 4);
  int*    cur   = (int*)alloc((size_t)NN * 4);
  int*    col   = (int*)alloc((size_t)NEE * 4);

  hipMemsetAsync(cnt, 0, (size_t)NN * 4, stream);
  hipMemsetAsync(cur, 0, (size_t)NN * 4, stream);

  const int EB = (NEE + 255) / 256;  // 2579
  k_hist<<<EB, 256, 0, stream>>>(ei, cnt);
  k_scan<<<1, 1024, 0, stream>>>(cnt, rp);
  k_scatter<<<EB, 256, 0, stream>>>(ei, rp, cur, col);
  k_cvt<<<NN * 256 / 4 / 256 + 256, 256, 0, stream>>>(x, W1, xh, W1T);  // 5256 blocks

  k_gemm1<<<NN / 16, 256, 0, stream>>>(xh, W1T, a_src1, a_dst1, h1h16, AS1, AD1);
  k_agg1<<<NN, 256, 0, stream>>>(rp, col, AS1, AD1, h1h16, b1, h1agg);

  k_gemm2<<<NN / 16, 256, 0, stream>>>(h1agg, W2, a_src2, a_dst2, h2h16, AS2, AD2);
  k_agg2<<<NN / 4, 256, 0, stream>>>(rp, col, AS2, AD2, h2h16, b2, h2agg);

  k_predot<<<NN / 16, 128, 0, stream>>>(h2agg, Wp1, bp1, AB);
  k_pairs<<<NP / 64, PB, 0, stream>>>(pairs, AB, Wp2, bp2, out);
}

// Round 18
// 296.885 us; speedup vs baseline: 1.7103x; 1.0340x over previous
//
#include <hip/hip_runtime.h>
#include <hip/hip_fp16.h>

#define NN 20000      // nodes
#define NE 640000     // edges (without self loops)
#define NEE 660000    // edges + self loops
#define NP 200000     // drug pairs
#define NEG 0.2f      // leaky relu slope

typedef _Float16 f16;
typedef __attribute__((ext_vector_type(4))) _Float16 f16x4;
typedef __attribute__((ext_vector_type(8))) _Float16 f16x8;
typedef __attribute__((ext_vector_type(4))) float f32x4;

// ---------------- CSR build ----------------
__global__ void k_hist(const int* __restrict__ ei, int* __restrict__ cnt) {
  int i = blockIdx.x * 256 + threadIdx.x;
  if (i >= NEE) return;
  int d = (i < NE) ? ei[NE + i] : (i - NE);
  atomicAdd(&cnt[d], 1);
}

__global__ __launch_bounds__(1024) void k_scan(const int* __restrict__ cnt, int* __restrict__ rp) {
  __shared__ int ps[1024];
  const int CH = 20;  // 1024*20 = 20480 >= 20000
  int t = threadIdx.x;
  int lo = t * CH, hi = lo + CH;
  if (hi > NN) hi = NN;
  if (lo > NN) lo = NN;
  int s = 0;
  for (int i = lo; i < hi; ++i) s += cnt[i];
  ps[t] = s;
  __syncthreads();
  for (int off = 1; off < 1024; off <<= 1) {
    int v = (t >= off) ? ps[t - off] : 0;
    __syncthreads();
    ps[t] += v;
    __syncthreads();
  }
  int run = (t > 0) ? ps[t - 1] : 0;
  for (int i = lo; i < hi; ++i) { rp[i] = run; run += cnt[i]; }
  if (t == 1023) rp[NN] = ps[1023];
}

__global__ void k_scatter(const int* __restrict__ ei, const int* __restrict__ rp,
                          int* __restrict__ cur, int* __restrict__ col) {
  int i = blockIdx.x * 256 + threadIdx.x;
  if (i >= NEE) return;
  int s, d;
  if (i < NE) { s = ei[i]; d = ei[NE + i]; } else { s = i - NE; d = s; }
  int pos = atomicAdd(&cur[d], 1);
  col[rp[d] + pos] = s;
}

// ---------------- convert: x -> fp16 (row-major), W1 -> fp16 TRANSPOSED [n][k] -----------
__global__ void k_cvt(const float* __restrict__ x, const float* __restrict__ W1,
                      f16* __restrict__ xh, f16* __restrict__ W1T) {
  int i = blockIdx.x * 256 + threadIdx.x;
  if (i < NN * 256 / 4) {
    float4 v = ((const float4*)x)[i];
    f16x4 h; h.x = (f16)v.x; h.y = (f16)v.y; h.z = (f16)v.z; h.w = (f16)v.w;
    *(f16x4*)(xh + (size_t)i * 4) = h;
  } else {
    int j = i - NN * 256 / 4;
    if (j < 256 * 256) {
      int r = j >> 8, c = j & 255;
      W1T[c * 256 + r] = (f16)W1[j];
    }
  }
}

// ---------------- prep: Wp2 [64][86] -> fp16 transposed padded [96][64]; bp2 -> [96] -----
__global__ void k_prep(const float* __restrict__ Wp2, const float* __restrict__ bp2,
                       f16* __restrict__ Wp2Th, float* __restrict__ bp2p) {
  int i = blockIdx.x * 256 + threadIdx.x;
  if (i < 96 * 64) {
    int o = i >> 6, t = i & 63;
    Wp2Th[o * 64 + t] = (o < 86) ? (f16)Wp2[t * 86 + o] : (f16)0.f;
  }
  if (i < 96) bp2p[i] = (i < 86) ? bp2[i] : 0.f;
}

// ---------------- GEMM1 v3 (MFMA): h1 = x @ W1 via mfma_f32_16x16x32_f16 ----------------
__global__ __launch_bounds__(256) void k_gemm1(
    const f16* __restrict__ xh, const f16* __restrict__ W1T,
    const float* __restrict__ as1, const float* __restrict__ ad1,
    __half* __restrict__ h1h16, float* __restrict__ AS1, float* __restrict__ AD1) {
  __shared__ f16 xs[16][264];     // 16 rows x 256 k, row stride 528B
  int tid = threadIdx.x;
  int base = blockIdx.x * 16;
  {
    int r = tid >> 4, ch = tid & 15;   // each thread stages 16 f16 (32B) of one row
    const uint4* src = (const uint4*)(xh + (size_t)(base + r) * 256 + ch * 16);
    uint4 v0 = src[0], v1 = src[1];
    *(uint4*)&xs[r][ch * 16] = v0;
    *(uint4*)&xs[r][ch * 16 + 8] = v1;
  }
  __syncthreads();
  int wv = tid >> 6, lane = tid & 63;
  int head = wv;
  int lr = lane & 15, lk = lane >> 4;
  f32x4 acc[4] = {{0.f,0.f,0.f,0.f},{0.f,0.f,0.f,0.f},{0.f,0.f,0.f,0.f},{0.f,0.f,0.f,0.f}};
#pragma unroll
  for (int k0 = 0; k0 < 256; k0 += 32) {
    f16x8 a = *(const f16x8*)&xs[lr][k0 + lk * 8];
#pragma unroll
    for (int nt = 0; nt < 4; ++nt) {
      int n = head * 64 + nt * 16 + lr;
      f16x8 b = *(const f16x8*)(W1T + (size_t)n * 256 + k0 + lk * 8);
      acc[nt] = __builtin_amdgcn_mfma_f32_16x16x32_f16(a, b, acc[nt], 0, 0, 0);
    }
  }
#pragma unroll
  for (int nt = 0; nt < 4; ++nt) {
    int cc = nt * 16 + lr;
#pragma unroll
    for (int r = 0; r < 4; ++r) {
      int row = lk * 4 + r;
      h1h16[((size_t)head * NN + base + row) * 64 + cc] = __float2half(acc[nt][r]);
    }
  }
#pragma unroll
  for (int r = 0; r < 4; ++r) {
    float ps = 0.f, pd = 0.f;
#pragma unroll
    for (int nt = 0; nt < 4; ++nt) {
      int cc = nt * 16 + lr;
      ps += acc[nt][r] * as1[head * 64 + cc];
      pd += acc[nt][r] * ad1[head * 64 + cc];
    }
#pragma unroll
    for (int off = 1; off < 16; off <<= 1) {
      ps += __shfl_xor(ps, off);
      pd += __shfl_xor(pd, off);
    }
    if (lr == 0) {
      int n = base + lk * 4 + r;
      AS1[n * 4 + head] = ps;
      AD1[n * 4 + head] = pd;
    }
  }
}

// ---------------- GAT layer-1 aggregation v4: 8 edges x 8 lanes, XCD-pinned, pipelined ---
__global__ __launch_bounds__(256, 4) void k_agg1(
    const int* __restrict__ rp, const int* __restrict__ col,
    const float* __restrict__ AS1, const float* __restrict__ AD1,
    const __half* __restrict__ h1h16, const float* __restrict__ b1,
    float* __restrict__ out) {
  int b = blockIdx.x;
  int xcd = b & 7;
  int head = xcd >> 1;
  int grp = (b >> 3) * 2 + (xcd & 1);      // 0..4999, bijective per head
  int wave = threadIdx.x >> 6, lane = threadIdx.x & 63;
  int n = grp * 4 + wave;
  int g = lane >> 3, c8 = (lane & 7) * 8;  // edge group 0..7, col base (8 fp16 = 16B)
  int e0 = rp[n], e1 = rp[n + 1];
  const __half* hs = h1h16 + (size_t)head * NN * 64;
  float adv = AD1[n * 4 + head];
  float acc[8] = {0.f,0.f,0.f,0.f,0.f,0.f,0.f,0.f};
  float den = 0.f;

  int ee = e0 + g;
  bool v = ee < e1;
  int ec = v ? ee : e1 - 1;
  int s = col[ec];
  float asv = AS1[s * 4 + head];

  for (int e = e0; e < e1; e += 8) {
    int een = e + 8 + g;
    bool vn = een < e1;
    int ecn = vn ? een : e1 - 1;
    int sn = col[ecn];
    float asn = AS1[sn * 4 + head];
    float ev = asv + adv;
    ev = fmaxf(ev, NEG * ev);              // leaky relu
    float p = v ? __expf(ev) : 0.f;
    float4 raw = *(const float4*)(hs + (size_t)s * 64 + c8);   // 16B = 8 fp16
    const __half2* hp = (const __half2*)&raw;
#pragma unroll
    for (int m = 0; m < 4; ++m) {
      float2 f = __half22float2(hp[m]);
      acc[m * 2]     += p * f.x;
      acc[m * 2 + 1] += p * f.y;
    }
    den += p;
    s = sn; asv = asn; v = vn;
  }
#pragma unroll
  for (int i = 0; i < 8; ++i) {
    acc[i] += __shfl_xor(acc[i], 8);
    acc[i] += __shfl_xor(acc[i], 16);
    acc[i] += __shfl_xor(acc[i], 32);
  }
  den += __shfl_xor(den, 8); den += __shfl_xor(den, 16); den += __shfl_xor(den, 32);
  if (lane < 8) {
    float inv = 1.f / den;
    int cbase = head * 64 + lane * 8;
    float o[8];
#pragma unroll
    for (int i = 0; i < 8; ++i) {
      float r = acc[i] * inv + b1[cbase + i];
      o[i] = r > 0.f ? r : __expf(r) - 1.f;
    }
    *(float4*)(out + (size_t)n * 256 + cbase) = *(float4*)&o[0];
    *(float4*)(out + (size_t)n * 256 + cbase + 4) = *(float4*)&o[4];
  }
}

// ---------------- GEMM2: h2 = h1act @ W2, fp16 store (gather-only tensor) + alphas -------
__global__ __launch_bounds__(256) void k_gemm2(
    const float* __restrict__ h1a, const float* __restrict__ W2,
    const float* __restrict__ as2, const float* __restrict__ ad2,
    __half* __restrict__ h2h16, float* __restrict__ AS2, float* __restrict__ AD2) {
  __shared__ float xsT[256][20];
  int tid = threadIdx.x;
  int c = tid & 63, w = tid >> 6;  // wave w handles rows 4w..4w+3
  int base = blockIdx.x * 16;
  for (int i = tid; i < 16 * 256; i += 256) {
    int r = i >> 8, k = i & 255;
    xsT[k][r] = h1a[(base + r) * 256 + k];
  }
  __syncthreads();
  float acc[4] = {0.f, 0.f, 0.f, 0.f};
#pragma unroll 2
  for (int k = 0; k < 256; ++k) {
    float wv = W2[k * 64 + c];
    float4 xv = *(const float4*)&xsT[k][w * 4];
    acc[0] += xv.x * wv; acc[1] += xv.y * wv; acc[2] += xv.z * wv; acc[3] += xv.w * wv;
  }
  float asv = as2[c], adv = ad2[c];
#pragma unroll
  for (int rr = 0; rr < 4; ++rr) {
    int row = base + w * 4 + rr;
    h2h16[(size_t)row * 64 + c] = __float2half(acc[rr]);
    float vs = acc[rr] * asv, vd = acc[rr] * adv;
#pragma unroll
    for (int off = 32; off > 0; off >>= 1) {
      vs += __shfl_xor(vs, off);
      vd += __shfl_xor(vd, off);
    }
    if (c == 0) { AS2[row] = vs; AD2[row] = vd; }
  }
}

// ---------------- GAT layer-2 aggregation v4: 8 edges x 8 lanes, pipelined ---------------
__global__ __launch_bounds__(256, 4) void k_agg2(
    const int* __restrict__ rp, const int* __restrict__ col,
    const float* __restrict__ AS2, const float* __restrict__ AD2,
    const __half* __restrict__ h2h16, const float* __restrict__ b2,
    float* __restrict__ out) {
  int wave = threadIdx.x >> 6, lane = threadIdx.x & 63;
  int n = blockIdx.x * 4 + wave;
  int g = lane >> 3, c8 = (lane & 7) * 8;
  int e0 = rp[n], e1 = rp[n + 1];
  float adv = AD2[n];
  float acc[8] = {0.f,0.f,0.f,0.f,0.f,0.f,0.f,0.f};
  float den = 0.f;

  int ee = e0 + g;
  bool v = ee < e1;
  int ec = v ? ee : e1 - 1;
  int s = col[ec];
  float asv = AS2[s];

  for (int e = e0; e < e1; e += 8) {
    int een = e + 8 + g;
    bool vn = een < e1;
    int ecn = vn ? een : e1 - 1;
    int sn = col[ecn];
    float asn = AS2[sn];
    float ev = asv + adv;
    ev = fmaxf(ev, NEG * ev);
    float p = v ? __expf(ev) : 0.f;
    float4 raw = *(const float4*)(h2h16 + (size_t)s * 64 + c8);
    const __half2* hp = (const __half2*)&raw;
#pragma unroll
    for (int m = 0; m < 4; ++m) {
      float2 f = __half22float2(hp[m]);
      acc[m * 2]     += p * f.x;
      acc[m * 2 + 1] += p * f.y;
    }
    den += p;
    s = sn; asv = asn; v = vn;
  }
#pragma unroll
  for (int i = 0; i < 8; ++i) {
    acc[i] += __shfl_xor(acc[i], 8);
    acc[i] += __shfl_xor(acc[i], 16);
    acc[i] += __shfl_xor(acc[i], 32);
  }
  den += __shfl_xor(den, 8); den += __shfl_xor(den, 16); den += __shfl_xor(den, 32);
  if (lane < 8) {
    float inv = 1.f / den;
    int cbase = lane * 8;
    float o[8];
#pragma unroll
    for (int i = 0; i < 8; ++i) {
      float r = acc[i] * inv + b2[cbase + i];
      o[i] = r > 0.f ? r : __expf(r) - 1.f;
    }
    *(float4*)(out + (size_t)n * 64 + cbase) = *(float4*)&o[0];
    *(float4*)(out + (size_t)n * 64 + cbase + 4) = *(float4*)&o[4];
  }
}

// ---------------- per-node pair-MLP layer-1 precompute ----------------
__global__ __launch_bounds__(128) void k_predot(
    const float* __restrict__ h2a, const float* __restrict__ Wp1,
    const float* __restrict__ bp1, float* __restrict__ AB) {
  __shared__ float xsT[64][20];   // [k][row], 16 rows, pad 20
  int c = threadIdx.x;            // 0..127
  int base = blockIdx.x * 16;
  for (int i = threadIdx.x; i < 16 * 64; i += 128) {
    int r = i >> 6, k = i & 63;
    xsT[k][r] = h2a[(size_t)(base + r) * 64 + k];
  }
  __syncthreads();
  int part = c >> 6, u = c & 63;
  float bv = (part == 0) ? bp1[u] : 0.f;
  float acc[16];
#pragma unroll
  for (int r = 0; r < 16; ++r) acc[r] = bv;
#pragma unroll 2
  for (int k = 0; k < 64; ++k) {
    float wv = Wp1[(size_t)(part * 64 + k) * 64 + u];  // coalesced per half-wave
    const float4* xr = (const float4*)&xsT[k][0];
    float4 x0 = xr[0], x1 = xr[1], x2 = xr[2], x3 = xr[3];
    acc[0] += x0.x * wv; acc[1] += x0.y * wv; acc[2] += x0.z * wv; acc[3] += x0.w * wv;
    acc[4] += x1.x * wv; acc[5] += x1.y * wv; acc[6] += x1.z * wv; acc[7] += x1.w * wv;
    acc[8] += x2.x * wv; acc[9] += x2.y * wv; acc[10] += x2.z * wv; acc[11] += x2.w * wv;
    acc[12] += x3.x * wv; acc[13] += x3.y * wv; acc[14] += x3.z * wv; acc[15] += x3.w * wv;
  }
#pragma unroll
  for (int r = 0; r < 16; ++r) AB[(size_t)(base + r) * 128 + c] = acc[r];
}

// ---------------- pair MLP v13: z-gather + MFMA layer 2 ----------------
// Round-17 diagnosis: layer 2's 2752 scalar FMA/thread = 14 us of pure VALU issue at
// 24% busy -> put it on the matrix cores. Per 64-pair block: phase 1 builds z in fp16
// LDS zh[64][72] (144B row stride: 16B-aligned f16x8, 2-way bank alias = free) from
// fp32 AB gathers (numerics preserved); phase 2 = 64x96x64 GEMM via 12 MFMA per wave
// (fragment recipe identical to round-16's validated k_gemm1). Wp2 pre-transposed to
// fp16 [96][64] (12 KB, L2-hot). LDS 9.2 KB -> occupancy wave-capped.
__global__ __launch_bounds__(256) void k_pairs(
    const int* __restrict__ pairs, const float* __restrict__ AB,
    const f16* __restrict__ Wp2Th, const float* __restrict__ bp2p,
    float* __restrict__ out) {
  __shared__ f16 zh[64][72];  // [pair][t]
  int tid = threadIdx.x;
  int pp = tid & 63, q = tid >> 6;   // pair within block, z-quarter
  int p = blockIdx.x * 64 + pp;
  int pi = pairs[2 * p], pj = pairs[2 * p + 1];

  // ---- phase 1: z quarter q = relu(A[pi] + B[pj]) -> fp16 LDS  (bp1 folded in A)
  {
    const float4* ar = (const float4*)(AB + (size_t)pi * 128 + q * 16);
    const float4* br = (const float4*)(AB + (size_t)pj * 128 + 64 + q * 16);
    f16 zv[16];
#pragma unroll
    for (int m = 0; m < 4; ++m) {
      float4 a = ar[m], b = br[m];
      zv[m * 4]     = (f16)fmaxf(a.x + b.x, 0.f);
      zv[m * 4 + 1] = (f16)fmaxf(a.y + b.y, 0.f);
      zv[m * 4 + 2] = (f16)fmaxf(a.z + b.z, 0.f);
      zv[m * 4 + 3] = (f16)fmaxf(a.w + b.w, 0.f);
    }
    *(uint4*)&zh[pp][q * 16] = *(uint4*)&zv[0];
    *(uint4*)&zh[pp][q * 16 + 8] = *(uint4*)&zv[8];
  }
  __syncthreads();

  // ---- phase 2: out-tile = z @ Wp2 via MFMA; wave wv owns pairs wv*16..wv*16+15
  int wv = tid >> 6, lane = tid & 63;
  int lr = lane & 15, lk = lane >> 4;
#pragma unroll
  for (int nt = 0; nt < 6; ++nt) {
    f32x4 acc = {0.f, 0.f, 0.f, 0.f};
#pragma unroll
    for (int k0 = 0; k0 < 64; k0 += 32) {
      f16x8 a = *(const f16x8*)&zh[wv * 16 + lr][k0 + lk * 8];
      f16x8 b = *(const f16x8*)(Wp2Th + (size_t)(nt * 16 + lr) * 64 + k0 + lk * 8);
      acc = __builtin_amdgcn_mfma_f32_16x16x32_f16(a, b, acc, 0, 0, 0);
    }
    int o = nt * 16 + lr;
    if (o < 86) {
      float bb = bp2p[o];
#pragma unroll
      for (int r = 0; r < 4; ++r) {
        int pr = blockIdx.x * 64 + wv * 16 + lk * 4 + r;
        out[(size_t)pr * 86 + o] = acc[r] + bb;
      }
    }
  }
}

extern "C" void kernel_launch(void* const* d_in, const int* in_sizes, int n_in,
                              void* d_out, int out_size, void* d_ws, size_t ws_size,
                              hipStream_t stream) {
  (void)in_sizes; (void)n_in; (void)out_size; (void)ws_size;
  const float* x      = (const float*)d_in[0];
  const int*   ei     = (const int*)d_in[1];
  const int*   pairs  = (const int*)d_in[2];
  const float* W1     = (const float*)d_in[3];
  const float* a_src1 = (const float*)d_in[4];
  const float* a_dst1 = (const float*)d_in[5];
  const float* b1     = (const float*)d_in[6];
  const float* W2     = (const float*)d_in[7];
  const float* a_src2 = (const float*)d_in[8];
  const float* a_dst2 = (const float*)d_in[9];
  const float* b2     = (const float*)d_in[10];
  const float* Wp1    = (const float*)d_in[11];
  const float* bp1    = (const float*)d_in[12];
  const float* Wp2    = (const float*)d_in[13];
  const float* bp2    = (const float*)d_in[14];
  float* out = (float*)d_out;

  char* w = (char*)d_ws;
  auto alloc = [&](size_t bytes) -> void* {
    void* pp = (void*)w;
    w += (bytes + 255) & ~(size_t)255;
    return pp;
  };
  __half* h1h16 = (__half*)alloc((size_t)NN * 256 * 2);  // head-major [4][NN][64] fp16
  float*  AS1   = (float*)alloc((size_t)NN * 4 * 4);
  float*  AD1   = (float*)alloc((size_t)NN * 4 * 4);
  float*  h1agg = (float*)alloc((size_t)NN * 256 * 4);
  __half* h2h16 = (__half*)alloc((size_t)NN * 64 * 2);   // fp16 gather copy
  float*  AS2   = (float*)alloc((size_t)NN * 4);
  float*  AD2   = (float*)alloc((size_t)NN * 4);
  float*  h2agg = (float*)alloc((size_t)NN * 64 * 4);
  float*  AB    = (float*)alloc((size_t)NN * 128 * 4);
  f16*    xh    = (f16*)alloc((size_t)NN * 256 * 2);     // fp16 copy of x
  f16*    W1T   = (f16*)alloc((size_t)256 * 256 * 2);    // fp16 W1 transposed [n][k]
  f16*    Wp2Th = (f16*)alloc((size_t)96 * 64 * 2);      // fp16 Wp2 transposed padded
  float*  bp2p  = (float*)alloc(96 * 4);
  int*    rp    = (int*)alloc((size_t)(NN + 1) * 4);
  int*    cnt   = (int*)alloc((size_t)NN * 4);
  int*    cur   = (int*)alloc((size_t)NN * 4);
  int*    col   = (int*)alloc((size_t)NEE * 4);

  hipMemsetAsync(cnt, 0, (size_t)NN * 4, stream);
  hipMemsetAsync(cur, 0, (size_t)NN * 4, stream);

  const int EB = (NEE + 255) / 256;  // 2579
  k_hist<<<EB, 256, 0, stream>>>(ei, cnt);
  k_scan<<<1, 1024, 0, stream>>>(cnt, rp);
  k_scatter<<<EB, 256, 0, stream>>>(ei, rp, cur, col);
  k_cvt<<<NN * 256 / 4 / 256 + 256, 256, 0, stream>>>(x, W1, xh, W1T);  // 5256 blocks
  k_prep<<<24, 256, 0, stream>>>(Wp2, bp2, Wp2Th, bp2p);

  k_gemm1<<<NN / 16, 256, 0, stream>>>(xh, W1T, a_src1, a_dst1, h1h16, AS1, AD1);
  k_agg1<<<NN, 256, 0, stream>>>(rp, col, AS1, AD1, h1h16, b1, h1agg);

  k_gemm2<<<NN / 16, 256, 0, stream>>>(h1agg, W2, a_src2, a_dst2, h2h16, AS2, AD2);
  k_agg2<<<NN / 4, 256, 0, stream>>>(rp, col, AS2, AD2, h2h16, b2, h2agg);

  k_predot<<<NN / 16, 128, 0, stream>>>(h2agg, Wp1, bp1, AB);
  k_pairs<<<NP / 64, 256, 0, stream>>>(pairs, AB, Wp2Th, bp2p, out);
}

// Round 20
// 267.466 us; speedup vs baseline: 1.8984x; 1.1100x over previous
//
#include <hip/hip_runtime.h>
#include <hip/hip_fp16.h>

#define NN 20000      // nodes
#define NE 640000     // edges (without self loops)
#define NEE 660000    // edges + self loops
#define NP 200000     // drug pairs
#define NEG 0.2f      // leaky relu slope

typedef _Float16 f16;
typedef __attribute__((ext_vector_type(4))) _Float16 f16x4;
typedef __attribute__((ext_vector_type(8))) _Float16 f16x8;
typedef __attribute__((ext_vector_type(4))) float f32x4;

// ---------------- CSR build ----------------
__global__ void k_hist(const int* __restrict__ ei, int* __restrict__ cnt) {
  int i = blockIdx.x * 256 + threadIdx.x;
  if (i >= NEE) return;
  int d = (i < NE) ? ei[NE + i] : (i - NE);
  atomicAdd(&cnt[d], 1);
}

__global__ __launch_bounds__(1024) void k_scan(const int* __restrict__ cnt, int* __restrict__ rp) {
  __shared__ int ps[1024];
  const int CH = 20;  // 1024*20 = 20480 >= 20000
  int t = threadIdx.x;
  int lo = t * CH, hi = lo + CH;
  if (hi > NN) hi = NN;
  if (lo > NN) lo = NN;
  int s = 0;
  for (int i = lo; i < hi; ++i) s += cnt[i];
  ps[t] = s;
  __syncthreads();
  for (int off = 1; off < 1024; off <<= 1) {
    int v = (t >= off) ? ps[t - off] : 0;
    __syncthreads();
    ps[t] += v;
    __syncthreads();
  }
  int run = (t > 0) ? ps[t - 1] : 0;
  for (int i = lo; i < hi; ++i) { rp[i] = run; run += cnt[i]; }
  if (t == 1023) rp[NN] = ps[1023];
}

__global__ void k_scatter(const int* __restrict__ ei, const int* __restrict__ rp,
                          int* __restrict__ cur, int* __restrict__ col) {
  int i = blockIdx.x * 256 + threadIdx.x;
  if (i >= NEE) return;
  int s, d;
  if (i < NE) { s = ei[i]; d = ei[NE + i]; } else { s = i - NE; d = s; }
  int pos = atomicAdd(&cur[d], 1);
  col[rp[d] + pos] = s;
}

// ---------------- convert: x -> fp16 (row-major), W1 -> fp16 TRANSPOSED [n][k] -----------
__global__ void k_cvt(const float* __restrict__ x, const float* __restrict__ W1,
                      f16* __restrict__ xh, f16* __restrict__ W1T) {
  int i = blockIdx.x * 256 + threadIdx.x;
  if (i < NN * 256 / 4) {
    float4 v = ((const float4*)x)[i];
    f16x4 h; h.x = (f16)v.x; h.y = (f16)v.y; h.z = (f16)v.z; h.w = (f16)v.w;
    *(f16x4*)(xh + (size_t)i * 4) = h;
  } else {
    int j = i - NN * 256 / 4;
    if (j < 256 * 256) {
      int r = j >> 8, c = j & 255;
      W1T[c * 256 + r] = (f16)W1[j];
    }
  }
}

// ---------------- prep: Wp2 -> fp16 [96][64]; bp2 -> [96]; W2 -> fp16 T [64][256] --------
__global__ void k_prep(const float* __restrict__ Wp2, const float* __restrict__ bp2,
                       const float* __restrict__ W2,
                       f16* __restrict__ Wp2Th, float* __restrict__ bp2p,
                       f16* __restrict__ W2T) {
  int i = blockIdx.x * 256 + threadIdx.x;
  if (i < 96 * 64) {
    int o = i >> 6, t = i & 63;
    Wp2Th[o * 64 + t] = (o < 86) ? (f16)Wp2[t * 86 + o] : (f16)0.f;
  }
  if (i < 96) bp2p[i] = (i < 86) ? bp2[i] : 0.f;
  if (i < 64 * 256) {
    int n = i >> 8, k = i & 255;
    W2T[n * 256 + k] = (f16)W2[k * 64 + n];
  }
}

// ---------------- GEMM1 v3 (MFMA): h1 = x @ W1 via mfma_f32_16x16x32_f16 ----------------
__global__ __launch_bounds__(256) void k_gemm1(
    const f16* __restrict__ xh, const f16* __restrict__ W1T,
    const float* __restrict__ as1, const float* __restrict__ ad1,
    __half* __restrict__ h1h16, float* __restrict__ AS1, float* __restrict__ AD1) {
  __shared__ f16 xs[16][264];     // 16 rows x 256 k, row stride 528B
  int tid = threadIdx.x;
  int base = blockIdx.x * 16;
  {
    int r = tid >> 4, ch = tid & 15;   // each thread stages 16 f16 (32B) of one row
    const uint4* src = (const uint4*)(xh + (size_t)(base + r) * 256 + ch * 16);
    uint4 v0 = src[0], v1 = src[1];
    *(uint4*)&xs[r][ch * 16] = v0;
    *(uint4*)&xs[r][ch * 16 + 8] = v1;
  }
  __syncthreads();
  int wv = tid >> 6, lane = tid & 63;
  int head = wv;
  int lr = lane & 15, lk = lane >> 4;
  f32x4 acc[4] = {{0.f,0.f,0.f,0.f},{0.f,0.f,0.f,0.f},{0.f,0.f,0.f,0.f},{0.f,0.f,0.f,0.f}};
#pragma unroll
  for (int k0 = 0; k0 < 256; k0 += 32) {
    f16x8 a = *(const f16x8*)&xs[lr][k0 + lk * 8];
#pragma unroll
    for (int nt = 0; nt < 4; ++nt) {
      int n = head * 64 + nt * 16 + lr;
      f16x8 b = *(const f16x8*)(W1T + (size_t)n * 256 + k0 + lk * 8);
      acc[nt] = __builtin_amdgcn_mfma_f32_16x16x32_f16(a, b, acc[nt], 0, 0, 0);
    }
  }
#pragma unroll
  for (int nt = 0; nt < 4; ++nt) {
    int cc = nt * 16 + lr;
#pragma unroll
    for (int r = 0; r < 4; ++r) {
      int row = lk * 4 + r;
      h1h16[((size_t)head * NN + base + row) * 64 + cc] = __float2half(acc[nt][r]);
    }
  }
#pragma unroll
  for (int r = 0; r < 4; ++r) {
    float ps = 0.f, pd = 0.f;
#pragma unroll
    for (int nt = 0; nt < 4; ++nt) {
      int cc = nt * 16 + lr;
      ps += acc[nt][r] * as1[head * 64 + cc];
      pd += acc[nt][r] * ad1[head * 64 + cc];
    }
#pragma unroll
    for (int off = 1; off < 16; off <<= 1) {
      ps += __shfl_xor(ps, off);
      pd += __shfl_xor(pd, off);
    }
    if (lr == 0) {
      int n = base + lk * 4 + r;
      AS1[n * 4 + head] = ps;
      AD1[n * 4 + head] = pd;
    }
  }
}

// ---------------- GAT layer-1 aggregation v5: 8x8, XCD-pinned, pipelined, fp16 out -------
__global__ __launch_bounds__(256, 4) void k_agg1(
    const int* __restrict__ rp, const int* __restrict__ col,
    const float* __restrict__ AS1, const float* __restrict__ AD1,
    const __half* __restrict__ h1h16, const float* __restrict__ b1,
    __half* __restrict__ out16) {
  int b = blockIdx.x;
  int xcd = b & 7;
  int head = xcd >> 1;
  int grp = (b >> 3) * 2 + (xcd & 1);      // 0..4999, bijective per head
  int wave = threadIdx.x >> 6, lane = threadIdx.x & 63;
  int n = grp * 4 + wave;
  int g = lane >> 3, c8 = (lane & 7) * 8;  // edge group 0..7, col base (8 fp16 = 16B)
  int e0 = rp[n], e1 = rp[n + 1];
  const __half* hs = h1h16 + (size_t)head * NN * 64;
  float adv = AD1[n * 4 + head];
  float acc[8] = {0.f,0.f,0.f,0.f,0.f,0.f,0.f,0.f};
  float den = 0.f;

  int ee = e0 + g;
  bool v = ee < e1;
  int ec = v ? ee : e1 - 1;
  int s = col[ec];
  float asv = AS1[s * 4 + head];

  for (int e = e0; e < e1; e += 8) {
    int een = e + 8 + g;
    bool vn = een < e1;
    int ecn = vn ? een : e1 - 1;
    int sn = col[ecn];
    float asn = AS1[sn * 4 + head];
    float ev = asv + adv;
    ev = fmaxf(ev, NEG * ev);              // leaky relu
    float p = v ? __expf(ev) : 0.f;
    float4 raw = *(const float4*)(hs + (size_t)s * 64 + c8);   // 16B = 8 fp16
    const __half2* hp = (const __half2*)&raw;
#pragma unroll
    for (int m = 0; m < 4; ++m) {
      float2 f = __half22float2(hp[m]);
      acc[m * 2]     += p * f.x;
      acc[m * 2 + 1] += p * f.y;
    }
    den += p;
    s = sn; asv = asn; v = vn;
  }
#pragma unroll
  for (int i = 0; i < 8; ++i) {
    acc[i] += __shfl_xor(acc[i], 8);
    acc[i] += __shfl_xor(acc[i], 16);
    acc[i] += __shfl_xor(acc[i], 32);
  }
  den += __shfl_xor(den, 8); den += __shfl_xor(den, 16); den += __shfl_xor(den, 32);
  if (lane < 8) {
    float inv = 1.f / den;
    int cbase = head * 64 + lane * 8;
    __half ho[8];
#pragma unroll
    for (int i = 0; i < 8; ++i) {
      float r = acc[i] * inv + b1[cbase + i];
      r = r > 0.f ? r : __expf(r) - 1.f;
      ho[i] = __float2half(r);
    }
    *(uint4*)(out16 + (size_t)n * 256 + cbase) = *(uint4*)&ho[0];
  }
}

// ---------------- GEMM2 v2 (MFMA): h2 = h1act @ W2 ----------------
__global__ __launch_bounds__(256) void k_gemm2(
    const f16* __restrict__ h1a16, const f16* __restrict__ W2T,
    const float* __restrict__ as2, const float* __restrict__ ad2,
    __half* __restrict__ h2h16, float* __restrict__ AS2, float* __restrict__ AD2) {
  __shared__ f16 xs[16][264];
  __shared__ float psL[4][16], pdL[4][16];
  int tid = threadIdx.x;
  int base = blockIdx.x * 16;
  {
    int r = tid >> 4, ch = tid & 15;
    const uint4* src = (const uint4*)(h1a16 + (size_t)(base + r) * 256 + ch * 16);
    uint4 v0 = src[0], v1 = src[1];
    *(uint4*)&xs[r][ch * 16] = v0;
    *(uint4*)&xs[r][ch * 16 + 8] = v1;
  }
  __syncthreads();
  int wv = tid >> 6, lane = tid & 63;
  int lr = lane & 15, lk = lane >> 4;
  f32x4 acc = {0.f, 0.f, 0.f, 0.f};
#pragma unroll
  for (int k0 = 0; k0 < 256; k0 += 32) {
    f16x8 a = *(const f16x8*)&xs[lr][k0 + lk * 8];
    f16x8 b = *(const f16x8*)(W2T + (size_t)(wv * 16 + lr) * 256 + k0 + lk * 8);
    acc = __builtin_amdgcn_mfma_f32_16x16x32_f16(a, b, acc, 0, 0, 0);
  }
  int cc = wv * 16 + lr;
  float asv = as2[cc], adv = ad2[cc];
  float psr[4], pdr[4];
#pragma unroll
  for (int r = 0; r < 4; ++r) {
    int row = lk * 4 + r;
    h2h16[(size_t)(base + row) * 64 + cc] = __float2half(acc[r]);
    float ps = acc[r] * asv, pd = acc[r] * adv;
#pragma unroll
    for (int off = 1; off < 16; off <<= 1) {
      ps += __shfl_xor(ps, off);
      pd += __shfl_xor(pd, off);
    }
    psr[r] = ps; pdr[r] = pd;
  }
  if (lr == 0) {
#pragma unroll
    for (int r = 0; r < 4; ++r) {
      psL[wv][lk * 4 + r] = psr[r];
      pdL[wv][lk * 4 + r] = pdr[r];
    }
  }
  __syncthreads();
  if (tid < 16) {
    AS2[base + tid] = psL[0][tid] + psL[1][tid] + psL[2][tid] + psL[3][tid];
    AD2[base + tid] = pdL[0][tid] + pdL[1][tid] + pdL[2][tid] + pdL[3][tid];
  }
}

// ---------------- GAT layer-2 aggregation v4: 8 edges x 8 lanes, pipelined ---------------
__global__ __launch_bounds__(256, 4) void k_agg2(
    const int* __restrict__ rp, const int* __restrict__ col,
    const float* __restrict__ AS2, const float* __restrict__ AD2,
    const __half* __restrict__ h2h16, const float* __restrict__ b2,
    float* __restrict__ out) {
  int wave = threadIdx.x >> 6, lane = threadIdx.x & 63;
  int n = blockIdx.x * 4 + wave;
  int g = lane >> 3, c8 = (lane & 7) * 8;
  int e0 = rp[n], e1 = rp[n + 1];
  float adv = AD2[n];
  float acc[8] = {0.f,0.f,0.f,0.f,0.f,0.f,0.f,0.f};
  float den = 0.f;

  int ee = e0 + g;
  bool v = ee < e1;
  int ec = v ? ee : e1 - 1;
  int s = col[ec];
  float asv = AS2[s];

  for (int e = e0; e < e1; e += 8) {
    int een = e + 8 + g;
    bool vn = een < e1;
    int ecn = vn ? een : e1 - 1;
    int sn = col[ecn];
    float asn = AS2[sn];
    float ev = asv + adv;
    ev = fmaxf(ev, NEG * ev);
    float p = v ? __expf(ev) : 0.f;
    float4 raw = *(const float4*)(h2h16 + (size_t)s * 64 + c8);
    const __half2* hp = (const __half2*)&raw;
#pragma unroll
    for (int m = 0; m < 4; ++m) {
      float2 f = __half22float2(hp[m]);
      acc[m * 2]     += p * f.x;
      acc[m * 2 + 1] += p * f.y;
    }
    den += p;
    s = sn; asv = asn; v = vn;
  }
#pragma unroll
  for (int i = 0; i < 8; ++i) {
    acc[i] += __shfl_xor(acc[i], 8);
    acc[i] += __shfl_xor(acc[i], 16);
    acc[i] += __shfl_xor(acc[i], 32);
  }
  den += __shfl_xor(den, 8); den += __shfl_xor(den, 16); den += __shfl_xor(den, 32);
  if (lane < 8) {
    float inv = 1.f / den;
    int cbase = lane * 8;
    float o[8];
#pragma unroll
    for (int i = 0; i < 8; ++i) {
      float r = acc[i] * inv + b2[cbase + i];
      o[i] = r > 0.f ? r : __expf(r) - 1.f;
    }
    *(float4*)(out + (size_t)n * 64 + cbase) = *(float4*)&o[0];
    *(float4*)(out + (size_t)n * 64 + cbase + 4) = *(float4*)&o[4];
  }
}

// ---------------- per-node pair-MLP layer-1 precompute ----------------
__global__ __launch_bounds__(128) void k_predot(
    const float* __restrict__ h2a, const float* __restrict__ Wp1,
    const float* __restrict__ bp1, float* __restrict__ AB) {
  __shared__ float xsT[64][20];   // [k][row], 16 rows, pad 20
  int c = threadIdx.x;            // 0..127
  int base = blockIdx.x * 16;
  for (int i = threadIdx.x; i < 16 * 64; i += 128) {
    int r = i >> 6, k = i & 63;
    xsT[k][r] = h2a[(size_t)(base + r) * 64 + k];
  }
  __syncthreads();
  int part = c >> 6, u = c & 63;
  float bv = (part == 0) ? bp1[u] : 0.f;
  float acc[16];
#pragma unroll
  for (int r = 0; r < 16; ++r) acc[r] = bv;
#pragma unroll 2
  for (int k = 0; k < 64; ++k) {
    float wv = Wp1[(size_t)(part * 64 + k) * 64 + u];  // coalesced per half-wave
    const float4* xr = (const float4*)&xsT[k][0];
    float4 x0 = xr[0], x1 = xr[1], x2 = xr[2], x3 = xr[3];
    acc[0] += x0.x * wv; acc[1] += x0.y * wv; acc[2] += x0.z * wv; acc[3] += x0.w * wv;
    acc[4] += x1.x * wv; acc[5] += x1.y * wv; acc[6] += x1.z * wv; acc[7] += x1.w * wv;
    acc[8] += x2.x * wv; acc[9] += x2.y * wv; acc[10] += x2.z * wv; acc[11] += x2.w * wv;
    acc[12] += x3.x * wv; acc[13] += x3.y * wv; acc[14] += x3.z * wv; acc[15] += x3.w * wv;
  }
#pragma unroll
  for (int r = 0; r < 16; ++r) AB[(size_t)(base + r) * 128 + c] = acc[r];
}

// ---------------- pair MLP v13: z-gather + MFMA layer 2 ----------------
__global__ __launch_bounds__(256) void k_pairs(
    const int* __restrict__ pairs, const float* __restrict__ AB,
    const f16* __restrict__ Wp2Th, const float* __restrict__ bp2p,
    float* __restrict__ out) {
  __shared__ f16 zh[64][72];  // [pair][t]
  int tid = threadIdx.x;
  int pp = tid & 63, q = tid >> 6;   // pair within block, z-quarter
  int p = blockIdx.x * 64 + pp;
  int pi = pairs[2 * p], pj = pairs[2 * p + 1];

  // ---- phase 1: z quarter q = relu(A[pi] + B[pj]) -> fp16 LDS  (bp1 folded in A)
  {
    const float4* ar = (const float4*)(AB + (size_t)pi * 128 + q * 16);
    const float4* br = (const float4*)(AB + (size_t)pj * 128 + 64 + q * 16);
    f16 zv[16];
#pragma unroll
    for (int m = 0; m < 4; ++m) {
      float4 a = ar[m], b = br[m];
      zv[m * 4]     = (f16)fmaxf(a.x + b.x, 0.f);
      zv[m * 4 + 1] = (f16)fmaxf(a.y + b.y, 0.f);
      zv[m * 4 + 2] = (f16)fmaxf(a.z + b.z, 0.f);
      zv[m * 4 + 3] = (f16)fmaxf(a.w + b.w, 0.f);
    }
    *(uint4*)&zh[pp][q * 16] = *(uint4*)&zv[0];
    *(uint4*)&zh[pp][q * 16 + 8] = *(uint4*)&zv[8];
  }
  __syncthreads();

  // ---- phase 2: out-tile = z @ Wp2 via MFMA; wave wv owns pairs wv*16..wv*16+15
  int wv = tid >> 6, lane = tid & 63;
  int lr = lane & 15, lk = lane >> 4;
#pragma unroll
  for (int nt = 0; nt < 6; ++nt) {
    f32x4 acc = {0.f, 0.f, 0.f, 0.f};
#pragma unroll
    for (int k0 = 0; k0 < 64; k0 += 32) {
      f16x8 a = *(const f16x8*)&zh[wv * 16 + lr][k0 + lk * 8];
      f16x8 b = *(const f16x8*)(Wp2Th + (size_t)(nt * 16 + lr) * 64 + k0 + lk * 8);
      acc = __builtin_amdgcn_mfma_f32_16x16x32_f16(a, b, acc, 0, 0, 0);
    }
    int o = nt * 16 + lr;
    if (o < 86) {
      float bb = bp2p[o];
#pragma unroll
      for (int r = 0; r < 4; ++r) {
        int pr = blockIdx.x * 64 + wv * 16 + lk * 4 + r;
        out[(size_t)pr * 86 + o] = acc[r] + bb;
      }
    }
  }
}

extern "C" void kernel_launch(void* const* d_in, const int* in_sizes, int n_in,
                              void* d_out, int out_size, void* d_ws, size_t ws_size,
                              hipStream_t stream) {
  (void)in_sizes; (void)n_in; (void)out_size; (void)ws_size;
  const float* x      = (const float*)d_in[0];
  const int*   ei     = (const int*)d_in[1];
  const int*   pairs  = (const int*)d_in[2];
  const float* W1     = (const float*)d_in[3];
  const float* a_src1 = (const float*)d_in[4];
  const float* a_dst1 = (const float*)d_in[5];
  const float* b1     = (const float*)d_in[6];
  const float* W2     = (const float*)d_in[7];
  const float* a_src2 = (const float*)d_in[8];
  const float* a_dst2 = (const float*)d_in[9];
  const float* b2     = (const float*)d_in[10];
  const float* Wp1    = (const float*)d_in[11];
  const float* bp1    = (const float*)d_in[12];
  const float* Wp2    = (const float*)d_in[13];
  const float* bp2    = (const float*)d_in[14];
  float* out = (float*)d_out;

  char* w = (char*)d_ws;
  auto alloc = [&](size_t bytes) -> void* {
    void* pp = (void*)w;
    w += (bytes + 255) & ~(size_t)255;
    return pp;
  };
  __half* h1h16 = (__half*)alloc((size_t)NN * 256 * 2);  // head-major [4][NN][64] fp16
  float*  AS1   = (float*)alloc((size_t)NN * 4 * 4);
  float*  AD1   = (float*)alloc((size_t)NN * 4 * 4);
  __half* h1a16 = (__half*)alloc((size_t)NN * 256 * 2);  // fp16 h1agg (gemm2 input)
  __half* h2h16 = (__half*)alloc((size_t)NN * 64 * 2);   // fp16 gather copy
  float*  AS2   = (float*)alloc((size_t)NN * 4);
  float*  AD2   = (float*)alloc((size_t)NN * 4);
  float*  h2agg = (float*)alloc((size_t)NN * 64 * 4);
  float*  AB    = (float*)alloc((size_t)NN * 128 * 4);
  f16*    xh    = (f16*)alloc((size_t)NN * 256 * 2);     // fp16 copy of x
  f16*    W1T   = (f16*)alloc((size_t)256 * 256 * 2);    // fp16 W1 transposed [n][k]
  f16*    Wp2Th = (f16*)alloc((size_t)96 * 64 * 2);      // fp16 Wp2 transposed padded
  float*  bp2p  = (float*)alloc(96 * 4);
  f16*    W2T   = (f16*)alloc((size_t)64 * 256 * 2);     // fp16 W2 transposed [n][k]
  int*    rp    = (int*)alloc((size_t)(NN + 1) * 4);
  int*    cnt   = (int*)alloc((size_t)NN * 4);
  int*    cur   = (int*)alloc((size_t)NN * 4);
  int*    col   = (int*)alloc((size_t)NEE * 4);

  (void)hipMemsetAsync(cnt, 0, (size_t)NN * 4, stream);
  (void)hipMemsetAsync(cur, 0, (size_t)NN * 4, stream);

  const int EB = (NEE + 255) / 256;  // 2579
  k_hist<<<EB, 256, 0, stream>>>(ei, cnt);
  k_scan<<<1, 1024, 0, stream>>>(cnt, rp);
  k_scatter<<<EB, 256, 0, stream>>>(ei, rp, cur, col);
  k_cvt<<<NN * 256 / 4 / 256 + 256, 256, 0, stream>>>(x, W1, xh, W1T);  // 5256 blocks
  k_prep<<<64, 256, 0, stream>>>(Wp2, bp2, W2, Wp2Th, bp2p, W2T);

  k_gemm1<<<NN / 16, 256, 0, stream>>>(xh, W1T, a_src1, a_dst1, h1h16, AS1, AD1);
  k_agg1<<<NN, 256, 0, stream>>>(rp, col, AS1, AD1, h1h16, b1, h1a16);

  k_gemm2<<<NN / 16, 256, 0, stream>>>((const f16*)h1a16, W2T, a_src2, a_dst2, h2h16, AS2, AD2);
  k_agg2<<<NN / 4, 256, 0, stream>>>(rp, col, AS2, AD2, h2h16, b2, h2agg);

  k_predot<<<NN / 16, 128, 0, stream>>>(h2agg, Wp1, bp1, AB);
  k_pairs<<<NP / 64, 256, 0, stream>>>(pairs, AB, Wp2Th, bp2p, out);
}